// Round 3
// baseline (740.601 us; speedup 1.0000x reference)
//
#include <hip/hip_runtime.h>
#include <math.h>

// Problem constants (fixed by the reference)
#define TOK    2048      // B*S
#define DMODEL 1024
#define NHEAD  16
#define HDIM   64
#define NEXP   8
#define DFFN   4096

typedef unsigned short u16;
typedef __attribute__((ext_vector_type(8))) short short8;   // 8 bf16 (4 VGPRs)
typedef __attribute__((ext_vector_type(4))) float floatx4;  // MFMA C/D

__device__ __forceinline__ float sigmoidf_(float x) { return 1.f / (1.f + __expf(-x)); }

__device__ __forceinline__ u16 f2bf(float f) {               // RNE fp32->bf16
  union { float f; unsigned u; } v; v.f = f;
  unsigned r = v.u + 0x7FFFu + ((v.u >> 16) & 1u);
  return (u16)(r >> 16);
}
__device__ __forceinline__ float bf2f(u16 h) {
  union { unsigned u; float f; } v; v.u = ((unsigned)h) << 16; return v.f;
}

// async global->LDS, 16B per lane; LDS dest = wave-uniform base + lane*16
__device__ __forceinline__ void gload16(const void* g, void* l) {
  __builtin_amdgcn_global_load_lds((const __attribute__((address_space(1))) void*)g,
                                   (__attribute__((address_space(3))) void*)l, 16, 0, 0);
}

// block = 256 threads (4 waves). Broadcast result to all threads.
__device__ __forceinline__ float blockReduceSum256(float val) {
  __shared__ float ws_[4];
  #pragma unroll
  for (int off = 32; off; off >>= 1) val += __shfl_down(val, off);
  int lane = threadIdx.x & 63, w = threadIdx.x >> 6;
  if (lane == 0) ws_[w] = val;
  __syncthreads();
  float r = ws_[0] + ws_[1] + ws_[2] + ws_[3];
  __syncthreads();
  return r;
}

// ---------------------------------------------------------------------------
// Prep mega-kernel (all independent input transforms, one launch):
//  blocks [0,2048):    src fp32 -> (src_hi, src_lo) split
//  blocks [2048,5120): QKV weight conv+transpose -> Wt3 hi/lo
//  blocks [5120,7168): gate_w / ow conv+transpose -> hi/lo
// ---------------------------------------------------------------------------
__global__ __launch_bounds__(256) void prep_kernel(
    const float* __restrict__ src, u16* __restrict__ Shi, u16* __restrict__ Slo,
    const float* __restrict__ Qw, const float* __restrict__ Kw, const float* __restrict__ Vw,
    u16* __restrict__ W3h, u16* __restrict__ W3l,
    const float* __restrict__ Gw, u16* __restrict__ Gh, u16* __restrict__ Gl,
    const float* __restrict__ Ow, u16* __restrict__ Oh, u16* __restrict__ Ol) {
  const int bid = blockIdx.x, tid = threadIdx.x;
  __shared__ float tile[32][33];
  if (bid < 2048) {                               // ---- split path
    const int i = bid * 256 + tid;
    const float4 v = ((const float4*)src)[i];
    const float f[4] = {v.x, v.y, v.z, v.w};
    union { u16 s[4]; uint2 u; } h, l;
    #pragma unroll
    for (int j = 0; j < 4; ++j) {
      h.s[j] = f2bf(f[j]);
      l.s[j] = f2bf(f[j] - bf2f(h.s[j]));
    }
    ((uint2*)Shi)[i] = h.u;
    ((uint2*)Slo)[i] = l.u;
    return;
  }
  const float* W; u16 *Whp, *Wlp; int n0, k0, ldk;
  if (bid < 5120) {                               // ---- QKV weights
    const int t = bid - 2048;
    const int z = t >> 5;                         // 0..95
    const int zz = z >> 5;                        // 0,1,2
    W = (zz == 0) ? Qw : (zz == 1) ? Kw : Vw;
    Whp = W3h + (size_t)zz * DMODEL * DMODEL;
    Wlp = W3l + (size_t)zz * DMODEL * DMODEL;
    n0 = (t & 31) * 32; k0 = (z & 31) * 32; ldk = DMODEL;
  } else {                                        // ---- gate_w / ow
    const int t = bid - 5120;
    const int t2 = t & 1023;
    if (t < 1024) { W = Gw; Whp = Gh; Wlp = Gl; }
    else          { W = Ow; Whp = Oh; Wlp = Ol; }
    n0 = (t2 & 31) * 32; k0 = (t2 >> 5) * 32; ldk = DMODEL;
  }
  const int r = tid >> 3, c4 = (tid & 7) * 4;
  const float4 v = *(const float4*)&W[(size_t)(k0 + r) * DMODEL + n0 + c4];
  tile[r][c4+0] = v.x; tile[r][c4+1] = v.y; tile[r][c4+2] = v.z; tile[r][c4+3] = v.w;
  __syncthreads();
  union { u16 s[4]; uint2 u; } h, l;
  #pragma unroll
  for (int j = 0; j < 4; ++j) {
    const float f = tile[c4 + j][r];
    h.s[j] = f2bf(f);
    l.s[j] = f2bf(f - bf2f(h.s[j]));
  }
  *(uint2*)&Whp[(size_t)(n0 + r) * ldk + k0 + c4] = h.u;
  *(uint2*)&Wlp[(size_t)(n0 + r) * ldk + k0 + c4] = l.u;
}

// ---------------------------------------------------------------------------
// Split-precision bf16 MFMA GEMM body: C[M,N] = A[M,K] @ W[K,N].
// acc += Ah*Wh + Al*Wh + Ah*Wl  (error ~2^-18, protects MoE routing).
// Tile 128(M) x TN(N), BK=64, 4 waves 2x2, 16x16x32 MFMA, chunk-swizzled LDS.
// EPI 0: Cf = acc. EPI 1: split(sigmoid(acc+bias)*mul). EPI 2: QKV (V transposed).
// ---------------------------------------------------------------------------
template<int EPI, int TN>
__device__ __forceinline__ void gemm_split_body(
    u16* Ah, u16* Al, u16* Bh, u16* Bl, int bx, int by,
    const u16* __restrict__ Ahi, const u16* __restrict__ Alo,
    const u16* __restrict__ Whi, const u16* __restrict__ Wlo,
    const float* __restrict__ bias, const float* __restrict__ mul,
    float* __restrict__ Cf, u16* __restrict__ Chi, u16* __restrict__ Clo,
    u16* __restrict__ Vth, u16* __restrict__ Vtl,
    int M, int N, int K) {
  constexpr int NF = TN / 32;                    // B n-frags per wave (2 or 4)
  const int tid = threadIdx.x;
  const int lane = tid & 63, wave = tid >> 6;
  const int row0 = by * 128, col0 = bx * TN;
  const int wm = (wave & 1) * 64, wn = (wave >> 1) * (TN / 2);
  const int mr = tid >> 3;                       // staging row 0..31 (+p*32)
  const int ksrc = (tid & 7) ^ ((tid >> 3) & 7); // swizzled source k-chunk
  const floatx4 zero = {0.f, 0.f, 0.f, 0.f};
  floatx4 acc[4][NF];
  #pragma unroll
  for (int i = 0; i < 4; ++i)
    #pragma unroll
    for (int j = 0; j < NF; ++j) acc[i][j] = zero;

  for (int k0 = 0; k0 < K; k0 += 64) {
    __syncthreads();
    #pragma unroll
    for (int p = 0; p < 4; ++p) {               // A: 128 rows
      const size_t ga = (size_t)(row0 + p * 32 + mr) * K + (k0 + ksrc * 8);
      const size_t off = (size_t)(p * 256 + wave * 64) * 16;
      gload16(Ahi + ga, (char*)Ah + off);
      gload16(Alo + ga, (char*)Al + off);
    }
    #pragma unroll
    for (int p = 0; p < NF; ++p) {              // B: TN rows
      const size_t gb = (size_t)(col0 + p * 32 + mr) * K + (k0 + ksrc * 8);
      const size_t off = (size_t)(p * 256 + wave * 64) * 16;
      gload16(Whi + gb, (char*)Bh + off);
      gload16(Wlo + gb, (char*)Bl + off);
    }
    __syncthreads();
    #pragma unroll
    for (int kk = 0; kk < 2; ++kk) {
      short8 ah[4], al[4], bh[NF], bl[NF];
      #pragma unroll
      for (int i = 0; i < 4; ++i) {
        const int ml = wm + i * 16 + (lane & 15);
        const int cm = (kk * 4 + (lane >> 4)) ^ (ml & 7);
        ah[i] = *(const short8*)&Ah[ml * 64 + cm * 8];
        al[i] = *(const short8*)&Al[ml * 64 + cm * 8];
      }
      #pragma unroll
      for (int j = 0; j < NF; ++j) {
        const int nl = wn + j * 16 + (lane & 15);
        const int cn = (kk * 4 + (lane >> 4)) ^ (nl & 7);
        bh[j] = *(const short8*)&Bh[nl * 64 + cn * 8];
        bl[j] = *(const short8*)&Bl[nl * 64 + cn * 8];
      }
      #pragma unroll
      for (int i = 0; i < 4; ++i)
        #pragma unroll
        for (int j = 0; j < NF; ++j) {
          acc[i][j] = __builtin_amdgcn_mfma_f32_16x16x32_bf16(ah[i], bh[j], acc[i][j], 0, 0, 0);
          acc[i][j] = __builtin_amdgcn_mfma_f32_16x16x32_bf16(al[i], bh[j], acc[i][j], 0, 0, 0);
          acc[i][j] = __builtin_amdgcn_mfma_f32_16x16x32_bf16(ah[i], bl[j], acc[i][j], 0, 0, 0);
        }
    }
  }
  const int cl = lane & 15, quad = lane >> 4;
  if (EPI == 2 && col0 >= 2048) {
    // V region: transposed store into Vt[bh][d][tok] (hi/lo), 8B packed.
    #pragma unroll
    for (int i = 0; i < 4; ++i)
      #pragma unroll
      for (int j = 0; j < NF; ++j) {
        const int dg = col0 + wn + j * 16 + cl - 2048;
        const int bh_ = dg >> 6, d = dg & 63;
        const int row = row0 + wm + i * 16 + quad * 4;   // +r, 4 consecutive toks
        const int b = row >> 10, t0 = row & 1023;
        union { u16 s[4]; uint2 u; } hh, ll;
        #pragma unroll
        for (int r = 0; r < 4; ++r) {
          const float v = acc[i][j][r];
          hh.s[r] = f2bf(v);
          ll.s[r] = f2bf(v - bf2f(hh.s[r]));
        }
        const size_t base = ((size_t)(b * 16 + bh_) * 64 + d) * 1024 + t0;
        *(uint2*)&Vth[base] = hh.u;
        *(uint2*)&Vtl[base] = ll.u;
      }
    return;
  }
  #pragma unroll
  for (int i = 0; i < 4; ++i)
    #pragma unroll
    for (int j = 0; j < NF; ++j) {
      const int col = col0 + wn + j * 16 + cl;
      #pragma unroll
      for (int r = 0; r < 4; ++r) {
        const int row = row0 + wm + i * 16 + quad * 4 + r;
        const float v = acc[i][j][r];
        if (EPI == 0) {
          Cf[(size_t)row * N + col] = v;
        } else if (EPI == 1) {
          const float s = sigmoidf_(v + bias[col]);
          const float g = s * mul[(size_t)row * N + col];
          const u16 hh = f2bf(g);
          Chi[(size_t)row * N + col] = hh;
          Clo[(size_t)row * N + col] = f2bf(g - bf2f(hh));
        } else {
          const u16 hh = f2bf(v);
          Chi[(size_t)row * N + col] = hh;
          Clo[(size_t)row * N + col] = f2bf(v - bf2f(hh));
        }
      }
    }
}

// Pure GEMM wrapper (QKV path).
template<int EPI, int TN>
__global__ __launch_bounds__(256, TN == 64 ? 3 : 2) void gemm_split_kernel(
    const u16* __restrict__ Ahi, const u16* __restrict__ Alo,
    const u16* __restrict__ Whi, const u16* __restrict__ Wlo,
    const float* __restrict__ bias, const float* __restrict__ mul,
    float* __restrict__ Cf, u16* __restrict__ Chi, u16* __restrict__ Clo,
    u16* __restrict__ Vth, u16* __restrict__ Vtl,
    int M, int N, int K) {
  __shared__ u16 Ah[128*64], Al[128*64], Bh[TN*64], Bl[TN*64];
  gemm_split_body<EPI, TN>(Ah, Al, Bh, Bl, blockIdx.x, blockIdx.y,
      Ahi, Alo, Whi, Wlo, bias, mul, Cf, Chi, Clo, Vth, Vtl, M, N, K);
}

// GEMM (2048x1024x1024, TN=64) + hosted w2-conversion strips.
// blocks [0,256): gemm; blocks [256,512): w2 conv (khalf selects K range).
// Underfilled gemm (256 blocks @ occ 3) lets conv blocks stream HBM alongside.
struct GemmShared { u16 Ah[128*64]; u16 Al[128*64]; u16 Bh[64*64]; u16 Bl[64*64]; };
template<int EPI>
__global__ __launch_bounds__(256, 3) void gemm_split_w2_kernel(
    const u16* __restrict__ Ahi, const u16* __restrict__ Alo,
    const u16* __restrict__ Whi, const u16* __restrict__ Wlo,
    const float* __restrict__ bias, const float* __restrict__ mul,
    float* __restrict__ Cf, u16* __restrict__ Chi, u16* __restrict__ Clo,
    const float* __restrict__ W2, u16* __restrict__ W2b, int khalf) {
  __shared__ union { GemmShared g; float tile[32][33]; } sm;
  const int bid = blockIdx.x;
  if (bid < 256) {
    gemm_split_body<EPI, 64>(sm.g.Ah, sm.g.Al, sm.g.Bh, sm.g.Bl, bid & 15, bid >> 4,
        Ahi, Alo, Whi, Wlo, bias, mul, Cf, Chi, Clo, nullptr, nullptr,
        TOK, DMODEL, DMODEL);
    return;
  }
  // w2 conv strip: 32 n-cols x 2048 k rows. w2[e][k][n] fp32 -> [e][n][k] bf16.
  const int t = bid - 256;                // 0..255
  const int e = t >> 5, n0 = (t & 31) * 32;
  const float* W = W2 + (size_t)e * DFFN * DMODEL;
  u16* O = W2b + (size_t)e * DMODEL * DFFN;
  const int r = threadIdx.x >> 3, c4 = (threadIdx.x & 7) * 4;
  for (int kt = 0; kt < 64; ++kt) {
    const int k0 = khalf * 2048 + kt * 32;
    __syncthreads();
    const float4 v = *(const float4*)&W[(size_t)(k0 + r) * DMODEL + n0 + c4];
    sm.tile[r][c4+0] = v.x; sm.tile[r][c4+1] = v.y;
    sm.tile[r][c4+2] = v.z; sm.tile[r][c4+3] = v.w;
    __syncthreads();
    union { u16 s[4]; uint2 u; } h4;
    #pragma unroll
    for (int j = 0; j < 4; ++j) h4.s[j] = f2bf(sm.tile[c4 + j][r]);
    *(uint2*)&O[(size_t)(n0 + r) * DFFN + k0 + c4] = h4.u;
  }
}

// ---------------------------------------------------------------------------
// Grouped MoE GEMM, plain bf16 MFMA. Tile 128(M) x TN(N), 4 waves 2x2.
// EPI 0 (ffn1): z = expert (8); full K. Hout = bf16(acc + bias[e][n]).
// EPI 1 (ffn2): z = e + 8*ks (16): 2-way split-K; P[ks][tok*N+col] = acc fp32.
// ---------------------------------------------------------------------------
template<int EPI, int TN>
__global__ __launch_bounds__(256, TN == 64 ? 4 : 3) void gemm_moe_kernel(
    const u16* __restrict__ A, const u16* __restrict__ Wt,
    const float* __restrict__ bias,
    const int* __restrict__ perm, const int* __restrict__ offs,
    const int* __restrict__ counts,
    u16* __restrict__ Hout, float* __restrict__ P0, float* __restrict__ P1,
    int N, int K) {
  constexpr int NF = TN / 32;
  const int z = blockIdx.z;
  const int e = (EPI == 0) ? z : (z & 7);
  const int ks = (EPI == 0) ? 0 : (z >> 3);
  const int ne = counts[e];
  const int tm = blockIdx.y;
  if (tm * 128 >= ne) return;
  const int kbeg = (EPI == 0) ? 0 : ks * (K >> 1);
  const int kend = (EPI == 0) ? K : kbeg + (K >> 1);
  __shared__ u16 As_[128*64], Bs_[TN*64];
  __shared__ int toks[128];
  const int tid = threadIdx.x;
  if (tid < 128) {
    const int idx = tm * 128 + tid;
    toks[tid] = perm[offs[e] + (idx < ne ? idx : 0)];
  }
  __syncthreads();
  const int lane = tid & 63, wave = tid >> 6;
  const int wm = (wave & 1) * 64, wn = (wave >> 1) * (TN / 2);
  const int mr = tid >> 3;
  const int ksrc = (tid & 7) ^ ((tid >> 3) & 7);
  size_t abase[4];
  #pragma unroll
  for (int p = 0; p < 4; ++p) abase[p] = (size_t)toks[p * 32 + mr] * K;
  const u16* We = Wt + (size_t)e * N * K;
  const int col0 = blockIdx.x * TN;
  const floatx4 zero = {0.f, 0.f, 0.f, 0.f};
  floatx4 acc[4][NF];
  #pragma unroll
  for (int i = 0; i < 4; ++i)
    #pragma unroll
    for (int j = 0; j < NF; ++j) acc[i][j] = zero;

  for (int k0 = kbeg; k0 < kend; k0 += 64) {
    __syncthreads();
    #pragma unroll
    for (int p = 0; p < 4; ++p) {
      const size_t off = (size_t)(p * 256 + wave * 64) * 16;
      gload16(A + abase[p] + (k0 + ksrc * 8), (char*)As_ + off);
    }
    #pragma unroll
    for (int p = 0; p < NF; ++p) {
      const size_t off = (size_t)(p * 256 + wave * 64) * 16;
      gload16(We + (size_t)(col0 + p * 32 + mr) * K + (k0 + ksrc * 8), (char*)Bs_ + off);
    }
    __syncthreads();
    #pragma unroll
    for (int kk = 0; kk < 2; ++kk) {
      short8 a[4], b[NF];
      #pragma unroll
      for (int i = 0; i < 4; ++i) {
        const int ml = wm + i * 16 + (lane & 15);
        const int cm = (kk * 4 + (lane >> 4)) ^ (ml & 7);
        a[i] = *(const short8*)&As_[ml * 64 + cm * 8];
      }
      #pragma unroll
      for (int j = 0; j < NF; ++j) {
        const int nl = wn + j * 16 + (lane & 15);
        const int cn = (kk * 4 + (lane >> 4)) ^ (nl & 7);
        b[j] = *(const short8*)&Bs_[nl * 64 + cn * 8];
      }
      #pragma unroll
      for (int i = 0; i < 4; ++i)
        #pragma unroll
        for (int j = 0; j < NF; ++j)
          acc[i][j] = __builtin_amdgcn_mfma_f32_16x16x32_bf16(a[i], b[j], acc[i][j], 0, 0, 0);
    }
  }
  const int cl = lane & 15, quad = lane >> 4;
  float* Pp = (EPI == 1) ? (ks ? P1 : P0) : nullptr;
  #pragma unroll
  for (int i = 0; i < 4; ++i)
    #pragma unroll
    for (int j = 0; j < NF; ++j) {
      const int col = col0 + wn + j * 16 + cl;
      #pragma unroll
      for (int r = 0; r < 4; ++r) {
        const int rl = wm + i * 16 + quad * 4 + r;
        if (tm * 128 + rl < ne) {
          const int tok = toks[rl];
          if (EPI == 0)
            Hout[(size_t)tok * N + col] = f2bf(acc[i][j][r] + bias[(size_t)e * N + col]);
          else
            Pp[(size_t)tok * N + col] = acc[i][j][r];
        }
      }
    }
}

// ---------------------------------------------------------------------------
// MFMA flash attention (split-bf16) + hosted w1-conversion strips.
// blocks [0,256): attn, grid-decomp (qt,h,b); blocks [256,768): w1 conv.
// block = 512 (8 waves). Attn @ occupancy 2 leaves one CU slot for conv.
// ---------------------------------------------------------------------------
struct AttnShared {
  u16 Kh[64*64], Kl[64*64], Vh[64*64], Vl[64*64];   // 32 KB
  u16 Ph[8][16*40], Pl[8][16*40];                   // 20 KB
};
__global__ __launch_bounds__(512, 2) void attn_w1conv_kernel(
    const u16* __restrict__ QKh, const u16* __restrict__ QKl,
    const u16* __restrict__ Vth, const u16* __restrict__ Vtl,
    const float* __restrict__ scale_w,
    float* __restrict__ AOf, u16* __restrict__ AOh, u16* __restrict__ AOl,
    const float* __restrict__ W1, u16* __restrict__ W1b) {
  __shared__ union { AttnShared a; float tile[64][65]; } sm;
  const int bid = blockIdx.x;
  const int tid = threadIdx.x;
  if (bid >= 256) {
    // w1 conv strip: 64 n-cols x full K=1024. w1[e][k][n] fp32 -> [e][n][k] bf16.
    const int s = bid - 256;                 // 0..511
    const int e = s >> 6, n0 = (s & 63) * 64;
    const float* W = W1 + (size_t)e * DMODEL * DFFN;
    u16* O = W1b + (size_t)e * DFFN * DMODEL;
    const int r = tid >> 3, c8 = (tid & 7) * 8;
    for (int k0 = 0; k0 < DMODEL; k0 += 64) {
      __syncthreads();
      const float4 v0 = *(const float4*)&W[(size_t)(k0 + r) * DFFN + n0 + c8];
      const float4 v1 = *(const float4*)&W[(size_t)(k0 + r) * DFFN + n0 + c8 + 4];
      sm.tile[r][c8+0] = v0.x; sm.tile[r][c8+1] = v0.y;
      sm.tile[r][c8+2] = v0.z; sm.tile[r][c8+3] = v0.w;
      sm.tile[r][c8+4] = v1.x; sm.tile[r][c8+5] = v1.y;
      sm.tile[r][c8+6] = v1.z; sm.tile[r][c8+7] = v1.w;
      __syncthreads();
      union { u16 s_[8]; uint4 u; } h8;
      #pragma unroll
      for (int j = 0; j < 8; ++j) h8.s_[j] = f2bf(sm.tile[c8 + j][r]);
      *(uint4*)&O[(size_t)(n0 + r) * DMODEL + k0 + c8] = h8.u;
    }
    return;
  }
  const int qt = bid & 7, h = (bid >> 3) & 15, b = bid >> 7;
  const int lane = tid & 63, wave = tid >> 6;
  const int i15 = lane & 15, quad = lane >> 4;
  const floatx4 zero = {0.f, 0.f, 0.f, 0.f};

  short8 qh[2], ql[2];
  const size_t qrow = ((size_t)b * 1024 + qt * 128 + wave * 16 + i15) * 3072 + h * 64;
  #pragma unroll
  for (int kk = 0; kk < 2; ++kk) {
    qh[kk] = *(const short8*)&QKh[qrow + kk * 32 + quad * 8];
    ql[kk] = *(const short8*)&QKl[qrow + kk * 32 + quad * 8];
  }
  float dot = 0.f;
  #pragma unroll
  for (int kk = 0; kk < 2; ++kk)
    #pragma unroll
    for (int j = 0; j < 8; ++j) {
      const float sw = scale_w[h * 64 + kk * 32 + quad * 8 + j];
      dot += (bf2f((u16)qh[kk][j]) + bf2f((u16)ql[kk][j])) * sw;
    }
  dot += __shfl_xor(dot, 16);
  dot += __shfl_xor(dot, 32);
  const float g = 2.f * sigmoidf_(dot) * 0.125f;
  float stot[4];
  #pragma unroll
  for (int r = 0; r < 4; ++r) stot[r] = __shfl(g, (lane >> 4) * 4 + r);

  float m_r[4], l_r[4];
  floatx4 Of[4];
  #pragma unroll
  for (int r = 0; r < 4; ++r) { m_r[r] = -1e30f; l_r[r] = 0.f; }
  #pragma unroll
  for (int f = 0; f < 4; ++f) Of[f] = zero;
  u16* PhW = sm.a.Ph[wave];
  u16* PlW = sm.a.Pl[wave];

  const int sr = tid >> 3;                         // staging row 0..63
  const int sc = ((tid & 7) ^ (sr & 7)) * 8;       // swizzled source k-chunk
  for (int kt = 0; kt < 16; ++kt) {
    __syncthreads();
    {
      const size_t off = (size_t)wave * 1024;      // bytes; +lane*16 by HW
      const size_t kg = ((size_t)b * 1024 + kt * 64 + sr) * 3072 + 1024 + h * 64 + sc;
      gload16(QKh + kg, (char*)sm.a.Kh + off);
      gload16(QKl + kg, (char*)sm.a.Kl + off);
      const size_t vg = ((size_t)(b * 16 + h) * 64 + sr) * 1024 + kt * 64 + sc;
      gload16(Vth + vg, (char*)sm.a.Vh + off);
      gload16(Vtl + vg, (char*)sm.a.Vl + off);
    }
    __syncthreads();
    float pm[4][4];
    #pragma unroll
    for (int jn = 0; jn < 4; ++jn) {
      floatx4 a = zero;
      #pragma unroll
      for (int kk = 0; kk < 2; ++kk) {
        const int n = jn * 16 + i15;
        const int ch = ((kk * 4 + quad) ^ (n & 7)) * 8;
        const short8 bh = *(const short8*)&sm.a.Kh[n * 64 + ch];
        const short8 bl = *(const short8*)&sm.a.Kl[n * 64 + ch];
        a = __builtin_amdgcn_mfma_f32_16x16x32_bf16(qh[kk], bh, a, 0, 0, 0);
        a = __builtin_amdgcn_mfma_f32_16x16x32_bf16(ql[kk], bh, a, 0, 0, 0);
        a = __builtin_amdgcn_mfma_f32_16x16x32_bf16(qh[kk], bl, a, 0, 0, 0);
      }
      #pragma unroll
      for (int r = 0; r < 4; ++r) pm[jn][r] = a[r] * stot[r];
    }
    float alpha[4];
    #pragma unroll
    for (int r = 0; r < 4; ++r) {
      float mx = fmaxf(fmaxf(pm[0][r], pm[1][r]), fmaxf(pm[2][r], pm[3][r]));
      mx = fmaxf(mx, __shfl_xor(mx, 1));
      mx = fmaxf(mx, __shfl_xor(mx, 2));
      mx = fmaxf(mx, __shfl_xor(mx, 4));
      mx = fmaxf(mx, __shfl_xor(mx, 8));
      const float mn = fmaxf(m_r[r], mx);
      alpha[r] = __expf(m_r[r] - mn);
      m_r[r] = mn;
      float rs = 0.f;
      #pragma unroll
      for (int jn = 0; jn < 4; ++jn) { pm[jn][r] = __expf(pm[jn][r] - mn); rs += pm[jn][r]; }
      rs += __shfl_xor(rs, 1);
      rs += __shfl_xor(rs, 2);
      rs += __shfl_xor(rs, 4);
      rs += __shfl_xor(rs, 8);
      l_r[r] = l_r[r] * alpha[r] + rs;
    }
    #pragma unroll
    for (int f = 0; f < 4; ++f)
      #pragma unroll
      for (int r = 0; r < 4; ++r) Of[f][r] *= alpha[r];
    #pragma unroll
    for (int kk = 0; kk < 2; ++kk) {
      #pragma unroll
      for (int jj = 0; jj < 2; ++jj) {
        const int jn = kk * 2 + jj;
        #pragma unroll
        for (int r = 0; r < 4; ++r) {
          const int a = (quad * 4 + r) * 40 + jj * 16 + i15;
          const u16 hh = f2bf(pm[jn][r]);
          PhW[a] = hh;
          PlW[a] = f2bf(pm[jn][r] - bf2f(hh));
        }
      }
      const short8 pah = *(const short8*)&PhW[i15 * 40 + quad * 8];
      const short8 pal = *(const short8*)&PlW[i15 * 40 + quad * 8];
      #pragma unroll
      for (int f = 0; f < 4; ++f) {
        const int d = f * 16 + i15;
        const int ch = ((kk * 4 + quad) ^ (d & 7)) * 8;
        const short8 vbh = *(const short8*)&sm.a.Vh[d * 64 + ch];
        const short8 vbl = *(const short8*)&sm.a.Vl[d * 64 + ch];
        Of[f] = __builtin_amdgcn_mfma_f32_16x16x32_bf16(pah, vbh, Of[f], 0, 0, 0);
        Of[f] = __builtin_amdgcn_mfma_f32_16x16x32_bf16(pal, vbh, Of[f], 0, 0, 0);
        Of[f] = __builtin_amdgcn_mfma_f32_16x16x32_bf16(pah, vbl, Of[f], 0, 0, 0);
      }
    }
  }
  float inv[4];
  #pragma unroll
  for (int r = 0; r < 4; ++r) inv[r] = 1.f / l_r[r];
  #pragma unroll
  for (int f = 0; f < 4; ++f)
    #pragma unroll
    for (int r = 0; r < 4; ++r) {
      const size_t row = (size_t)b * 1024 + qt * 128 + wave * 16 + quad * 4 + r;
      const int col = h * 64 + f * 16 + i15;
      const float val = Of[f][r] * inv[r];
      AOf[row * 1024 + col] = val;
      const u16 hh = f2bf(val);
      AOh[row * 1024 + col] = hh;
      AOl[row * 1024 + col] = f2bf(val - bf2f(hh));
    }
}

// ---------------------------------------------------------------------------
// x = LN(a + b) * g + beta -> fp32 + bf16; then wave 0 computes the MoE router
// for this token, replicating the old moe_gate_kernel bit-exactly (same fp32
// values read from LDS, same FMA order, same shuffle reduction tree).
// ---------------------------------------------------------------------------
__global__ __launch_bounds__(256) void ln_add_router_kernel(
    const float* __restrict__ A, const float* __restrict__ Bp,
    const float* __restrict__ g, const float* __restrict__ beta,
    float* __restrict__ outf, u16* __restrict__ outh,
    const float* __restrict__ gw, const float* __restrict__ gb,
    int* __restrict__ e_sel) {
  __shared__ float xrow[DMODEL];
  int t = blockIdx.x, tid = threadIdx.x;
  const float* a = A + (size_t)t * DMODEL;
  const float* b = Bp + (size_t)t * DMODEL;
  float v[4]; float s = 0.f;
  #pragma unroll
  for (int i = 0; i < 4; ++i) { int d = tid + i*256; v[i] = a[d] + b[d]; s += v[i]; }
  s = blockReduceSum256(s);
  float mean = s * (1.f/1024.f);
  float q = 0.f;
  #pragma unroll
  for (int i = 0; i < 4; ++i) { float df = v[i]-mean; q += df*df; }
  q = blockReduceSum256(q);
  float rstd = rsqrtf(q*(1.f/1024.f) + 1e-5f);
  #pragma unroll
  for (int i = 0; i < 4; ++i) {
    int d = tid + i*256;
    float val = (v[i]-mean)*rstd*g[d] + beta[d];
    outf[(size_t)t*DMODEL + d] = val;
    outh[(size_t)t*DMODEL + d] = f2bf(val);
    xrow[d] = val;
  }
  __syncthreads();
  if (tid < 64) {
    float acc[NEXP] = {};
    for (int d = tid; d < DMODEL; d += 64) {
      float xv = xrow[d];
      const float* gr = gw + (size_t)d * NEXP;
      #pragma unroll
      for (int e = 0; e < NEXP; ++e) acc[e] += xv * gr[e];
    }
    #pragma unroll
    for (int e = 0; e < NEXP; ++e) {
      #pragma unroll
      for (int off = 32; off; off >>= 1) acc[e] += __shfl_down(acc[e], off);
    }
    if (tid == 0) {
      float lg[NEXP];
      #pragma unroll
      for (int e = 0; e < NEXP; ++e) lg[e] = acc[e] + gb[e];
      int i1 = 0;
      for (int e = 1; e < NEXP; ++e) if (lg[e] > lg[i1]) i1 = e;
      int i2 = -1;
      for (int e = 0; e < NEXP; ++e) {
        if (e == i1) continue;
        if (i2 < 0 || lg[e] > lg[i2]) i2 = e;
      }
      e_sel[t] = (i1 > i2) ? i1 : i2;
    }
  }
}

// ---------------------------------------------------------------------------
// Final fused kernel: y = (p0+p1 + b2[e])*rs[e] + x ; out = LN(x + y, n2)
// ---------------------------------------------------------------------------
__global__ __launch_bounds__(256) void ln_final_kernel(
    const float* __restrict__ X, const float* __restrict__ P0,
    const float* __restrict__ P1, const float* __restrict__ B2,
    const float* __restrict__ rsv, const int* __restrict__ e_sel,
    const float* __restrict__ g, const float* __restrict__ beta,
    float* __restrict__ out) {
  int t = blockIdx.x, tid = threadIdx.x;
  const int e = e_sel[t];
  const float rse = rsv[e];
  const float* b2e = B2 + (size_t)e * DMODEL;
  const int d0 = tid * 4;
  const size_t base = (size_t)t * DMODEL + d0;
  const float4 xv = *(const float4*)&X[base];
  const float4 p0v = *(const float4*)&P0[base];
  const float4 p1v = *(const float4*)&P1[base];
  const float4 bv = *(const float4*)&b2e[d0];
  float v[4]; float s = 0.f;
  v[0] = 2.f*xv.x + (p0v.x + p1v.x + bv.x) * rse;
  v[1] = 2.f*xv.y + (p0v.y + p1v.y + bv.y) * rse;
  v[2] = 2.f*xv.z + (p0v.z + p1v.z + bv.z) * rse;
  v[3] = 2.f*xv.w + (p0v.w + p1v.w + bv.w) * rse;
  s = v[0] + v[1] + v[2] + v[3];
  s = blockReduceSum256(s);
  float mean = s * (1.f/1024.f);
  float q = 0.f;
  #pragma unroll
  for (int i = 0; i < 4; ++i) { float df = v[i]-mean; q += df*df; }
  q = blockReduceSum256(q);
  float rstd = rsqrtf(q*(1.f/1024.f) + 1e-5f);
  const float4 g4 = *(const float4*)&g[d0];
  const float4 be4 = *(const float4*)&beta[d0];
  float4 o;
  o.x = (v[0]-mean)*rstd*g4.x + be4.x;
  o.y = (v[1]-mean)*rstd*g4.y + be4.y;
  o.z = (v[2]-mean)*rstd*g4.z + be4.z;
  o.w = (v[3]-mean)*rstd*g4.w + be4.w;
  *(float4*)&out[base] = o;
}

__global__ __launch_bounds__(256) void moe_group_kernel(
    const int* __restrict__ e_sel, int* __restrict__ perm,
    int* __restrict__ g_offs, int* __restrict__ g_counts) {
  __shared__ int cnt[NEXP], offs[NEXP], cur[NEXP];
  int tid = threadIdx.x;
  if (tid < NEXP) cnt[tid] = 0;
  __syncthreads();
  for (int t = tid; t < TOK; t += 256) atomicAdd(&cnt[e_sel[t]], 1);
  __syncthreads();
  if (tid == 0) {
    int run = 0;
    for (int e = 0; e < NEXP; ++e) { offs[e] = run; cur[e] = run; run += cnt[e]; }
  }
  __syncthreads();
  if (tid < NEXP) { g_offs[tid] = offs[tid]; g_counts[tid] = cnt[tid]; }
  for (int t = tid; t < TOK; t += 256) {
    int pos = atomicAdd(&cur[e_sel[t]], 1);
    perm[pos] = t;
  }
}

// LN over DFF (per selected expert) + exact-erf GELU, in place on bf16 h.
__global__ __launch_bounds__(256) void moe_ln_gelu_kernel(
    u16* __restrict__ H, const float* __restrict__ ln_g,
    const float* __restrict__ ln_b, const int* __restrict__ e_sel) {
  int t = blockIdx.x, tid = threadIdx.x;
  int e = e_sel[t];
  u16* hp = H + (size_t)t * DFFN;
  float v[16]; float s = 0.f;
  #pragma unroll
  for (int i = 0; i < 4; ++i) {
    const int d = i * 1024 + tid * 4;
    union { uint2 u; u16 q[4]; } hv;
    hv.u = *(const uint2*)&hp[d];
    #pragma unroll
    for (int j = 0; j < 4; ++j) { v[i*4+j] = bf2f(hv.q[j]); s += v[i*4+j]; }
  }
  s = blockReduceSum256(s);
  float mean = s * (1.f/4096.f);
  float q = 0.f;
  #pragma unroll
  for (int i = 0; i < 16; ++i) { float df = v[i]-mean; q += df*df; }
  q = blockReduceSum256(q);
  float rstd = rsqrtf(q*(1.f/4096.f) + 1e-5f);
  const float* gg = ln_g + (size_t)e * DFFN;
  const float* bb = ln_b + (size_t)e * DFFN;
  #pragma unroll
  for (int i = 0; i < 4; ++i) {
    const int d = i * 1024 + tid * 4;
    const float4 g4 = *(const float4*)&gg[d];
    const float4 b4 = *(const float4*)&bb[d];
    const float gf[4] = {g4.x, g4.y, g4.z, g4.w};
    const float bf[4] = {b4.x, b4.y, b4.z, b4.w};
    union { uint2 u; u16 q[4]; } ov;
    #pragma unroll
    for (int j = 0; j < 4; ++j) {
      float xx = (v[i*4+j]-mean)*rstd*gf[j] + bf[j];
      ov.q[j] = f2bf(0.5f * xx * (1.f + erff(xx * 0.7071067811865475f)));
    }
    *(uint2*)&hp[d] = ov.u;
  }
}

// ---------------------------------------------------------------------------
extern "C" void kernel_launch(void* const* d_in, const int* in_sizes, int n_in,
                              void* d_out, int out_size, void* d_ws, size_t ws_size,
                              hipStream_t stream) {
  (void)in_sizes; (void)n_in; (void)out_size; (void)ws_size;
  const float* src    = (const float*)d_in[0];
  const float* qw     = (const float*)d_in[1];
  const float* kw     = (const float*)d_in[2];
  const float* vw     = (const float*)d_in[3];
  const float* ow     = (const float*)d_in[4];
  const float* gate_w = (const float*)d_in[5];
  const float* gate_b = (const float*)d_in[6];
  const float* scale_w= (const float*)d_in[7];
  const float* n1_g   = (const float*)d_in[8];
  const float* n1_b   = (const float*)d_in[9];
  const float* n2_g   = (const float*)d_in[10];
  const float* n2_b   = (const float*)d_in[11];
  const float* mgw    = (const float*)d_in[12];
  const float* mgb    = (const float*)d_in[13];
  const float* w1     = (const float*)d_in[14];
  const float* b1     = (const float*)d_in[15];
  const float* ln_g   = (const float*)d_in[16];
  const float* ln_b   = (const float*)d_in[17];
  const float* w2     = (const float*)d_in[18];
  const float* b2     = (const float*)d_in[19];
  const float* rs     = (const float*)d_in[20];

  char* ws = (char*)d_ws;
  const size_t MB = 1024 * 1024;
  // flat layout (no aliasing; ws >= 512 MB per harness fill)
  u16*   src_hi = (u16*)(ws + 0*MB);    // 4
  u16*   src_lo = (u16*)(ws + 4*MB);    // 4
  u16*   Wt3_hi = (u16*)(ws + 8*MB);    // 6
  u16*   Wt3_lo = (u16*)(ws + 14*MB);   // 6
  u16*   gw_hi  = (u16*)(ws + 20*MB);   // 2
  u16*   gw_lo  = (u16*)(ws + 22*MB);   // 2
  u16*   ow_hi  = (u16*)(ws + 24*MB);   // 2
  u16*   ow_lo  = (u16*)(ws + 26*MB);   // 2
  u16*   W1A    = (u16*)(ws + 28*MB);   // 64
  u16*   W2A    = (u16*)(ws + 92*MB);   // 64
  u16*   qkv_hi = (u16*)(ws + 156*MB);  // 12
  u16*   qkv_lo = (u16*)(ws + 168*MB);  // 12
  u16*   Vt_hi  = (u16*)(ws + 180*MB);  // 4
  u16*   Vt_lo  = (u16*)(ws + 184*MB);  // 4
  float* ao     = (float*)(ws + 188*MB);// 8
  u16*   ao_hi  = (u16*)(ws + 196*MB);  // 4
  u16*   ao_lo  = (u16*)(ws + 200*MB);  // 4
  u16*   gb_hi  = (u16*)(ws + 204*MB);  // 4
  u16*   gb_lo  = (u16*)(ws + 208*MB);  // 4
  float* proj   = (float*)(ws + 212*MB);// 8
  float* x      = (float*)(ws + 220*MB);// 8
  u16*   x_hi   = (u16*)(ws + 228*MB);  // 4
  u16*   h      = (u16*)(ws + 232*MB);  // 16
  float* p0     = (float*)(ws + 248*MB);// 8
  float* p1     = (float*)(ws + 256*MB);// 8
  int*   e_sel  = (int*)(ws + 264*MB);
  int*   perm   = e_sel + TOK;
  int*   offs   = perm + TOK;
  int*   cnts   = offs + NEXP;

  dim3 blk(256);

  // 1. all input transforms in one launch
  prep_kernel<<<7168, blk, 0, stream>>>(src, src_hi, src_lo,
      qw, kw, vw, Wt3_hi, Wt3_lo, gate_w, gw_hi, gw_lo, ow, ow_hi, ow_lo);

  // 2. fused QKV GEMM (V written directly transposed)
  gemm_split_kernel<2,64><<<dim3(48,16), blk, 0, stream>>>(src_hi, src_lo,
      Wt3_hi, Wt3_lo, nullptr, nullptr, nullptr, qkv_hi, qkv_lo, Vt_hi, Vt_lo,
      TOK, 3072, DMODEL);

  // 3. flash attention + hosted w1 conversion
  attn_w1conv_kernel<<<768, dim3(512), 0, stream>>>(
      qkv_hi, qkv_lo, Vt_hi, Vt_lo, scale_w, ao, ao_hi, ao_lo, w1, W1A);

  // 4. gate GEMM + hosted w2 conversion (K half 0)
  gemm_split_w2_kernel<1><<<512, blk, 0, stream>>>(ao_hi, ao_lo, gw_hi, gw_lo,
      gate_b, ao, nullptr, gb_hi, gb_lo, w2, W2A, 0);

  // 5. ow GEMM + hosted w2 conversion (K half 1)
  gemm_split_w2_kernel<0><<<512, blk, 0, stream>>>(gb_hi, gb_lo, ow_hi, ow_lo,
      nullptr, nullptr, proj, nullptr, nullptr, w2, W2A, 1);

  // 6. x = LN(src + proj) (+bf16) + router (bit-exact replica of moe_gate)
  ln_add_router_kernel<<<TOK, blk, 0, stream>>>(src, proj, n1_g, n1_b, x, x_hi,
      mgw, mgb, e_sel);

  // 7. grouping
  moe_group_kernel<<<1, blk, 0, stream>>>(e_sel, perm, offs, cnts);

  // 8. FFN1, all 8 experts in one launch
  gemm_moe_kernel<0,128><<<dim3(DFFN/128, 16, 8), blk, 0, stream>>>(
      x_hi, W1A, b1, perm, offs, cnts, h, nullptr, nullptr, DFFN, DMODEL);

  // 9. LN+GELU
  moe_ln_gelu_kernel<<<TOK, blk, 0, stream>>>(h, ln_g, ln_b, e_sel);

  // 10. FFN2, all 8 experts x 2-way split-K in one launch
  gemm_moe_kernel<1,64><<<dim3(DMODEL/64, 16, 16), blk, 0, stream>>>(
      h, W2A, nullptr, perm, offs, cnts, nullptr, p0, p1, DMODEL, DFFN);

  // 11. out = LN(x + ((p0+p1+b2[e])*rs[e] + x), n2)
  ln_final_kernel<<<TOK, blk, 0, stream>>>(x, p0, p1, b2, rs, e_sel, n2_g, n2_b,
      (float*)d_out);
}

// Round 4
// 713.287 us; speedup vs baseline: 1.0383x; 1.0383x over previous
//
#include <hip/hip_runtime.h>
#include <math.h>

// Problem constants (fixed by the reference)
#define TOK    2048      // B*S
#define DMODEL 1024
#define NHEAD  16
#define HDIM   64
#define NEXP   8
#define DFFN   4096

typedef unsigned short u16;
typedef __attribute__((ext_vector_type(8))) short short8;   // 8 bf16 (4 VGPRs)
typedef __attribute__((ext_vector_type(4))) float floatx4;  // MFMA C/D

__device__ __forceinline__ float sigmoidf_(float x) { return 1.f / (1.f + __expf(-x)); }

__device__ __forceinline__ u16 f2bf(float f) {               // RNE fp32->bf16
  union { float f; unsigned u; } v; v.f = f;
  unsigned r = v.u + 0x7FFFu + ((v.u >> 16) & 1u);
  return (u16)(r >> 16);
}
__device__ __forceinline__ float bf2f(u16 h) {
  union { unsigned u; float f; } v; v.u = ((unsigned)h) << 16; return v.f;
}

// async global->LDS, 16B per lane; LDS dest = wave-uniform base + lane*16
__device__ __forceinline__ void gload16(const void* g, void* l) {
  __builtin_amdgcn_global_load_lds((const __attribute__((address_space(1))) void*)g,
                                   (__attribute__((address_space(3))) void*)l, 16, 0, 0);
}

// block = 256 threads (4 waves). Broadcast result to all threads.
__device__ __forceinline__ float blockReduceSum256(float val) {
  __shared__ float ws_[4];
  #pragma unroll
  for (int off = 32; off; off >>= 1) val += __shfl_down(val, off);
  int lane = threadIdx.x & 63, w = threadIdx.x >> 6;
  if (lane == 0) ws_[w] = val;
  __syncthreads();
  float r = ws_[0] + ws_[1] + ws_[2] + ws_[3];
  __syncthreads();
  return r;
}

// ---------------------------------------------------------------------------
// Prep mega-kernel (all streaming input transforms, one BW-bound launch):
//  blocks [0,2048):      src fp32 -> (src_hi, src_lo) split
//  blocks [2048,5120):   QKV weight conv+transpose -> Wt3 hi/lo  (32x32 tiles)
//  blocks [5120,7168):   gate_w / ow conv+transpose -> hi/lo     (32x32 tiles)
//  blocks [7168,15360):  w1 conv+transpose -> W1b bf16           (64x64 tiles)
// All paths are pure streaming (no MFMA, no long barrier chains) -> no
// co-scheduling pathology (round-3 lesson: never mix conv strips with
// barrier-synced MFMA loops).
// ---------------------------------------------------------------------------
__global__ __launch_bounds__(256) void prep_kernel(
    const float* __restrict__ src, u16* __restrict__ Shi, u16* __restrict__ Slo,
    const float* __restrict__ Qw, const float* __restrict__ Kw, const float* __restrict__ Vw,
    u16* __restrict__ W3h, u16* __restrict__ W3l,
    const float* __restrict__ Gw, u16* __restrict__ Gh, u16* __restrict__ Gl,
    const float* __restrict__ Ow, u16* __restrict__ Oh, u16* __restrict__ Ol,
    const float* __restrict__ W1, u16* __restrict__ W1b) {
  const int bid = blockIdx.x, tid = threadIdx.x;
  __shared__ float tile[64][65];
  if (bid < 2048) {                               // ---- split path
    const int i = bid * 256 + tid;
    const float4 v = ((const float4*)src)[i];
    const float f[4] = {v.x, v.y, v.z, v.w};
    union { u16 s[4]; uint2 u; } h, l;
    #pragma unroll
    for (int j = 0; j < 4; ++j) {
      h.s[j] = f2bf(f[j]);
      l.s[j] = f2bf(f[j] - bf2f(h.s[j]));
    }
    ((uint2*)Shi)[i] = h.u;
    ((uint2*)Slo)[i] = l.u;
    return;
  }
  if (bid < 7168) {                               // ---- 32x32 split weight conv
    const float* W; u16 *Whp, *Wlp; int n0, k0;
    if (bid < 5120) {                             // QKV weights
      const int t = bid - 2048;
      const int z = t >> 5;                       // 0..95
      const int zz = z >> 5;                      // 0,1,2
      W = (zz == 0) ? Qw : (zz == 1) ? Kw : Vw;
      Whp = W3h + (size_t)zz * DMODEL * DMODEL;
      Wlp = W3l + (size_t)zz * DMODEL * DMODEL;
      n0 = (t & 31) * 32; k0 = (z & 31) * 32;
    } else {                                      // gate_w / ow
      const int t = bid - 5120;
      const int t2 = t & 1023;
      if (t < 1024) { W = Gw; Whp = Gh; Wlp = Gl; }
      else          { W = Ow; Whp = Oh; Wlp = Ol; }
      n0 = (t2 & 31) * 32; k0 = (t2 >> 5) * 32;
    }
    const int r = tid >> 3, c4 = (tid & 7) * 4;
    const float4 v = *(const float4*)&W[(size_t)(k0 + r) * DMODEL + n0 + c4];
    tile[r][c4+0] = v.x; tile[r][c4+1] = v.y; tile[r][c4+2] = v.z; tile[r][c4+3] = v.w;
    __syncthreads();
    union { u16 s[4]; uint2 u; } h, l;
    #pragma unroll
    for (int j = 0; j < 4; ++j) {
      const float f = tile[c4 + j][r];
      h.s[j] = f2bf(f);
      l.s[j] = f2bf(f - bf2f(h.s[j]));
    }
    *(uint2*)&Whp[(size_t)(n0 + r) * DMODEL + k0 + c4] = h.u;
    *(uint2*)&Wlp[(size_t)(n0 + r) * DMODEL + k0 + c4] = l.u;
    return;
  }
  // ---- w1 conv: 64x64 tile. w1[e][k][n] fp32 -> W1b[e][n][k] bf16.
  const int bid2 = bid - 7168;                    // 0..8191
  const int e = bid2 >> 10;                       // 1024 blocks/expert
  const int rem = bid2 & 1023;
  const int n0 = (rem & 63) * 64;                 // 64 n-tiles
  const int k0 = (rem >> 6) * 64;                 // 16 k-tiles
  const float* W = W1 + (size_t)e * DMODEL * DFFN;
  u16* O = W1b + (size_t)e * DFFN * DMODEL;
  const int r = tid >> 2, c16 = (tid & 3) * 16;
  #pragma unroll
  for (int jj = 0; jj < 4; ++jj) {
    const float4 v = *(const float4*)&W[(size_t)(k0 + r) * DFFN + n0 + c16 + jj * 4];
    tile[r][c16 + jj*4 + 0] = v.x; tile[r][c16 + jj*4 + 1] = v.y;
    tile[r][c16 + jj*4 + 2] = v.z; tile[r][c16 + jj*4 + 3] = v.w;
  }
  __syncthreads();
  union { u16 s[8]; uint4 u; } o0, o1;
  #pragma unroll
  for (int j = 0; j < 8; ++j) o0.s[j] = f2bf(tile[c16 + j][r]);
  #pragma unroll
  for (int j = 0; j < 8; ++j) o1.s[j] = f2bf(tile[c16 + 8 + j][r]);
  *(uint4*)&O[(size_t)(n0 + r) * DMODEL + k0 + c16]     = o0.u;
  *(uint4*)&O[(size_t)(n0 + r) * DMODEL + k0 + c16 + 8] = o1.u;
}

// ---------------------------------------------------------------------------
// Split-precision bf16 MFMA GEMM body: C[M,N] = A[M,K] @ W[K,N].
// acc += Ah*Wh + Al*Wh + Ah*Wl  (error ~2^-18, protects MoE routing).
// Tile 128(M) x TN(N), BK=64, 4 waves 2x2, 16x16x32 MFMA, chunk-swizzled LDS.
// EPI 0: Cf = acc. EPI 1: split(sigmoid(acc+bias)*mul). EPI 2: QKV (V transposed).
// ---------------------------------------------------------------------------
template<int EPI, int TN>
__device__ __forceinline__ void gemm_split_body(
    u16* Ah, u16* Al, u16* Bh, u16* Bl, int bx, int by,
    const u16* __restrict__ Ahi, const u16* __restrict__ Alo,
    const u16* __restrict__ Whi, const u16* __restrict__ Wlo,
    const float* __restrict__ bias, const float* __restrict__ mul,
    float* __restrict__ Cf, u16* __restrict__ Chi, u16* __restrict__ Clo,
    u16* __restrict__ Vth, u16* __restrict__ Vtl,
    int M, int N, int K) {
  constexpr int NF = TN / 32;                    // B n-frags per wave (2 or 4)
  const int tid = threadIdx.x;
  const int lane = tid & 63, wave = tid >> 6;
  const int row0 = by * 128, col0 = bx * TN;
  const int wm = (wave & 1) * 64, wn = (wave >> 1) * (TN / 2);
  const int mr = tid >> 3;                       // staging row 0..31 (+p*32)
  const int ksrc = (tid & 7) ^ ((tid >> 3) & 7); // swizzled source k-chunk
  const floatx4 zero = {0.f, 0.f, 0.f, 0.f};
  floatx4 acc[4][NF];
  #pragma unroll
  for (int i = 0; i < 4; ++i)
    #pragma unroll
    for (int j = 0; j < NF; ++j) acc[i][j] = zero;

  for (int k0 = 0; k0 < K; k0 += 64) {
    __syncthreads();
    #pragma unroll
    for (int p = 0; p < 4; ++p) {               // A: 128 rows
      const size_t ga = (size_t)(row0 + p * 32 + mr) * K + (k0 + ksrc * 8);
      const size_t off = (size_t)(p * 256 + wave * 64) * 16;
      gload16(Ahi + ga, (char*)Ah + off);
      gload16(Alo + ga, (char*)Al + off);
    }
    #pragma unroll
    for (int p = 0; p < NF; ++p) {              // B: TN rows
      const size_t gb = (size_t)(col0 + p * 32 + mr) * K + (k0 + ksrc * 8);
      const size_t off = (size_t)(p * 256 + wave * 64) * 16;
      gload16(Whi + gb, (char*)Bh + off);
      gload16(Wlo + gb, (char*)Bl + off);
    }
    __syncthreads();
    #pragma unroll
    for (int kk = 0; kk < 2; ++kk) {
      short8 ah[4], al[4], bh[NF], bl[NF];
      #pragma unroll
      for (int i = 0; i < 4; ++i) {
        const int ml = wm + i * 16 + (lane & 15);
        const int cm = (kk * 4 + (lane >> 4)) ^ (ml & 7);
        ah[i] = *(const short8*)&Ah[ml * 64 + cm * 8];
        al[i] = *(const short8*)&Al[ml * 64 + cm * 8];
      }
      #pragma unroll
      for (int j = 0; j < NF; ++j) {
        const int nl = wn + j * 16 + (lane & 15);
        const int cn = (kk * 4 + (lane >> 4)) ^ (nl & 7);
        bh[j] = *(const short8*)&Bh[nl * 64 + cn * 8];
        bl[j] = *(const short8*)&Bl[nl * 64 + cn * 8];
      }
      #pragma unroll
      for (int i = 0; i < 4; ++i)
        #pragma unroll
        for (int j = 0; j < NF; ++j) {
          acc[i][j] = __builtin_amdgcn_mfma_f32_16x16x32_bf16(ah[i], bh[j], acc[i][j], 0, 0, 0);
          acc[i][j] = __builtin_amdgcn_mfma_f32_16x16x32_bf16(al[i], bh[j], acc[i][j], 0, 0, 0);
          acc[i][j] = __builtin_amdgcn_mfma_f32_16x16x32_bf16(ah[i], bl[j], acc[i][j], 0, 0, 0);
        }
    }
  }
  const int cl = lane & 15, quad = lane >> 4;
  if (EPI == 2 && col0 >= 2048) {
    // V region: transposed store into Vt[bh][d][tok] (hi/lo), 8B packed.
    #pragma unroll
    for (int i = 0; i < 4; ++i)
      #pragma unroll
      for (int j = 0; j < NF; ++j) {
        const int dg = col0 + wn + j * 16 + cl - 2048;
        const int bh_ = dg >> 6, d = dg & 63;
        const int row = row0 + wm + i * 16 + quad * 4;   // +r, 4 consecutive toks
        const int b = row >> 10, t0 = row & 1023;
        union { u16 s[4]; uint2 u; } hh, ll;
        #pragma unroll
        for (int r = 0; r < 4; ++r) {
          const float v = acc[i][j][r];
          hh.s[r] = f2bf(v);
          ll.s[r] = f2bf(v - bf2f(hh.s[r]));
        }
        const size_t base = ((size_t)(b * 16 + bh_) * 64 + d) * 1024 + t0;
        *(uint2*)&Vth[base] = hh.u;
        *(uint2*)&Vtl[base] = ll.u;
      }
    return;
  }
  #pragma unroll
  for (int i = 0; i < 4; ++i)
    #pragma unroll
    for (int j = 0; j < NF; ++j) {
      const int col = col0 + wn + j * 16 + cl;
      #pragma unroll
      for (int r = 0; r < 4; ++r) {
        const int row = row0 + wm + i * 16 + quad * 4 + r;
        const float v = acc[i][j][r];
        if (EPI == 0) {
          Cf[(size_t)row * N + col] = v;
        } else if (EPI == 1) {
          const float s = sigmoidf_(v + bias[col]);
          const float g = s * mul[(size_t)row * N + col];
          const u16 hh = f2bf(g);
          Chi[(size_t)row * N + col] = hh;
          Clo[(size_t)row * N + col] = f2bf(g - bf2f(hh));
        } else {
          const u16 hh = f2bf(v);
          Chi[(size_t)row * N + col] = hh;
          Clo[(size_t)row * N + col] = f2bf(v - bf2f(hh));
        }
      }
    }
}

// Pure GEMM wrapper (QKV path).
template<int EPI, int TN>
__global__ __launch_bounds__(256, TN == 64 ? 3 : 2) void gemm_split_kernel(
    const u16* __restrict__ Ahi, const u16* __restrict__ Alo,
    const u16* __restrict__ Whi, const u16* __restrict__ Wlo,
    const float* __restrict__ bias, const float* __restrict__ mul,
    float* __restrict__ Cf, u16* __restrict__ Chi, u16* __restrict__ Clo,
    u16* __restrict__ Vth, u16* __restrict__ Vtl,
    int M, int N, int K) {
  __shared__ u16 Ah[128*64], Al[128*64], Bh[TN*64], Bl[TN*64];
  gemm_split_body<EPI, TN>(Ah, Al, Bh, Bl, blockIdx.x, blockIdx.y,
      Ahi, Alo, Whi, Wlo, bias, mul, Cf, Chi, Clo, Vth, Vtl, M, N, K);
}

// GEMM (2048x1024x1024, TN=64) + hosted w2-conversion strips.
// blocks [0,256): gemm; blocks [256,512): w2 conv (khalf selects K range).
// Works (round-3 A/B): gemm blocks sit 3-deep per CU so TLP absorbs the
// VMEM competition from the conv strips.
struct GemmShared { u16 Ah[128*64]; u16 Al[128*64]; u16 Bh[64*64]; u16 Bl[64*64]; };
template<int EPI>
__global__ __launch_bounds__(256, 3) void gemm_split_w2_kernel(
    const u16* __restrict__ Ahi, const u16* __restrict__ Alo,
    const u16* __restrict__ Whi, const u16* __restrict__ Wlo,
    const float* __restrict__ bias, const float* __restrict__ mul,
    float* __restrict__ Cf, u16* __restrict__ Chi, u16* __restrict__ Clo,
    const float* __restrict__ W2, u16* __restrict__ W2b, int khalf) {
  __shared__ union { GemmShared g; float tile[32][33]; } sm;
  const int bid = blockIdx.x;
  if (bid < 256) {
    gemm_split_body<EPI, 64>(sm.g.Ah, sm.g.Al, sm.g.Bh, sm.g.Bl, bid & 15, bid >> 4,
        Ahi, Alo, Whi, Wlo, bias, mul, Cf, Chi, Clo, nullptr, nullptr,
        TOK, DMODEL, DMODEL);
    return;
  }
  // w2 conv strip: 32 n-cols x 2048 k rows. w2[e][k][n] fp32 -> [e][n][k] bf16.
  const int t = bid - 256;                // 0..255
  const int e = t >> 5, n0 = (t & 31) * 32;
  const float* W = W2 + (size_t)e * DFFN * DMODEL;
  u16* O = W2b + (size_t)e * DMODEL * DFFN;
  const int r = threadIdx.x >> 3, c4 = (threadIdx.x & 7) * 4;
  for (int kt = 0; kt < 64; ++kt) {
    const int k0 = khalf * 2048 + kt * 32;
    __syncthreads();
    const float4 v = *(const float4*)&W[(size_t)(k0 + r) * DMODEL + n0 + c4];
    sm.tile[r][c4+0] = v.x; sm.tile[r][c4+1] = v.y;
    sm.tile[r][c4+2] = v.z; sm.tile[r][c4+3] = v.w;
    __syncthreads();
    union { u16 s[4]; uint2 u; } h4;
    #pragma unroll
    for (int j = 0; j < 4; ++j) h4.s[j] = f2bf(sm.tile[c4 + j][r]);
    *(uint2*)&O[(size_t)(n0 + r) * DFFN + k0 + c4] = h4.u;
  }
}

// ---------------------------------------------------------------------------
// Grouped MoE GEMM, plain bf16 MFMA. Tile 128(M) x TN(N), 4 waves 2x2.
// EPI 0 (ffn1): z = expert (8); full K. Hout = bf16(acc + bias[e][n]).
// EPI 1 (ffn2): z = e + 8*ks (16): 2-way split-K; P[ks][tok*N+col] = acc fp32.
// ---------------------------------------------------------------------------
template<int EPI, int TN>
__global__ __launch_bounds__(256, TN == 64 ? 4 : 3) void gemm_moe_kernel(
    const u16* __restrict__ A, const u16* __restrict__ Wt,
    const float* __restrict__ bias,
    const int* __restrict__ perm, const int* __restrict__ offs,
    const int* __restrict__ counts,
    u16* __restrict__ Hout, float* __restrict__ P0, float* __restrict__ P1,
    int N, int K) {
  constexpr int NF = TN / 32;
  const int z = blockIdx.z;
  const int e = (EPI == 0) ? z : (z & 7);
  const int ks = (EPI == 0) ? 0 : (z >> 3);
  const int ne = counts[e];
  const int tm = blockIdx.y;
  if (tm * 128 >= ne) return;
  const int kbeg = (EPI == 0) ? 0 : ks * (K >> 1);
  const int kend = (EPI == 0) ? K : kbeg + (K >> 1);
  __shared__ u16 As_[128*64], Bs_[TN*64];
  __shared__ int toks[128];
  const int tid = threadIdx.x;
  if (tid < 128) {
    const int idx = tm * 128 + tid;
    toks[tid] = perm[offs[e] + (idx < ne ? idx : 0)];
  }
  __syncthreads();
  const int lane = tid & 63, wave = tid >> 6;
  const int wm = (wave & 1) * 64, wn = (wave >> 1) * (TN / 2);
  const int mr = tid >> 3;
  const int ksrc = (tid & 7) ^ ((tid >> 3) & 7);
  size_t abase[4];
  #pragma unroll
  for (int p = 0; p < 4; ++p) abase[p] = (size_t)toks[p * 32 + mr] * K;
  const u16* We = Wt + (size_t)e * N * K;
  const int col0 = blockIdx.x * TN;
  const floatx4 zero = {0.f, 0.f, 0.f, 0.f};
  floatx4 acc[4][NF];
  #pragma unroll
  for (int i = 0; i < 4; ++i)
    #pragma unroll
    for (int j = 0; j < NF; ++j) acc[i][j] = zero;

  for (int k0 = kbeg; k0 < kend; k0 += 64) {
    __syncthreads();
    #pragma unroll
    for (int p = 0; p < 4; ++p) {
      const size_t off = (size_t)(p * 256 + wave * 64) * 16;
      gload16(A + abase[p] + (k0 + ksrc * 8), (char*)As_ + off);
    }
    #pragma unroll
    for (int p = 0; p < NF; ++p) {
      const size_t off = (size_t)(p * 256 + wave * 64) * 16;
      gload16(We + (size_t)(col0 + p * 32 + mr) * K + (k0 + ksrc * 8), (char*)Bs_ + off);
    }
    __syncthreads();
    #pragma unroll
    for (int kk = 0; kk < 2; ++kk) {
      short8 a[4], b[NF];
      #pragma unroll
      for (int i = 0; i < 4; ++i) {
        const int ml = wm + i * 16 + (lane & 15);
        const int cm = (kk * 4 + (lane >> 4)) ^ (ml & 7);
        a[i] = *(const short8*)&As_[ml * 64 + cm * 8];
      }
      #pragma unroll
      for (int j = 0; j < NF; ++j) {
        const int nl = wn + j * 16 + (lane & 15);
        const int cn = (kk * 4 + (lane >> 4)) ^ (nl & 7);
        b[j] = *(const short8*)&Bs_[nl * 64 + cn * 8];
      }
      #pragma unroll
      for (int i = 0; i < 4; ++i)
        #pragma unroll
        for (int j = 0; j < NF; ++j)
          acc[i][j] = __builtin_amdgcn_mfma_f32_16x16x32_bf16(a[i], b[j], acc[i][j], 0, 0, 0);
    }
  }
  const int cl = lane & 15, quad = lane >> 4;
  float* Pp = (EPI == 1) ? (ks ? P1 : P0) : nullptr;
  #pragma unroll
  for (int i = 0; i < 4; ++i)
    #pragma unroll
    for (int j = 0; j < NF; ++j) {
      const int col = col0 + wn + j * 16 + cl;
      #pragma unroll
      for (int r = 0; r < 4; ++r) {
        const int rl = wm + i * 16 + quad * 4 + r;
        if (tm * 128 + rl < ne) {
          const int tok = toks[rl];
          if (EPI == 0)
            Hout[(size_t)tok * N + col] = f2bf(acc[i][j][r] + bias[(size_t)e * N + col]);
          else
            Pp[(size_t)tok * N + col] = acc[i][j][r];
        }
      }
    }
}

// ---------------------------------------------------------------------------
// MFMA flash attention, split-bf16 (error ~1e-5: protects router decisions).
// grid = (S/128, H, B), block = 512 (8 waves; wave w owns q-rows w*16..w*16+15).
// PURE kernel — no hosted conv strips (round-3 lesson: BW-streaming blocks
// co-resident with this barrier-synced staging loop inflate it ~3x).
// ---------------------------------------------------------------------------
__global__ __launch_bounds__(512, 2) void attn_mfma_kernel(
    const u16* __restrict__ QKh, const u16* __restrict__ QKl,
    const u16* __restrict__ Vth, const u16* __restrict__ Vtl,
    const float* __restrict__ scale_w,
    float* __restrict__ AOf, u16* __restrict__ AOh, u16* __restrict__ AOl) {
  const int qt = blockIdx.x, h = blockIdx.y, b = blockIdx.z;
  __shared__ u16 Kh[64*64], Kl[64*64], Vh[64*64], Vl[64*64];   // 32 KB
  __shared__ u16 Ph[8][16*40], Pl[8][16*40];                   // 20 KB
  const int tid = threadIdx.x, lane = tid & 63, wave = tid >> 6;
  const int i15 = lane & 15, quad = lane >> 4;
  const floatx4 zero = {0.f, 0.f, 0.f, 0.f};

  short8 qh[2], ql[2];
  const size_t qrow = ((size_t)b * 1024 + qt * 128 + wave * 16 + i15) * 3072 + h * 64;
  #pragma unroll
  for (int kk = 0; kk < 2; ++kk) {
    qh[kk] = *(const short8*)&QKh[qrow + kk * 32 + quad * 8];
    ql[kk] = *(const short8*)&QKl[qrow + kk * 32 + quad * 8];
  }
  float dot = 0.f;
  #pragma unroll
  for (int kk = 0; kk < 2; ++kk)
    #pragma unroll
    for (int j = 0; j < 8; ++j) {
      const float sw = scale_w[h * 64 + kk * 32 + quad * 8 + j];
      dot += (bf2f((u16)qh[kk][j]) + bf2f((u16)ql[kk][j])) * sw;
    }
  dot += __shfl_xor(dot, 16);
  dot += __shfl_xor(dot, 32);
  const float g = 2.f * sigmoidf_(dot) * 0.125f;
  float stot[4];
  #pragma unroll
  for (int r = 0; r < 4; ++r) stot[r] = __shfl(g, (lane >> 4) * 4 + r);

  float m_r[4], l_r[4];
  floatx4 Of[4];
  #pragma unroll
  for (int r = 0; r < 4; ++r) { m_r[r] = -1e30f; l_r[r] = 0.f; }
  #pragma unroll
  for (int f = 0; f < 4; ++f) Of[f] = zero;
  u16* PhW = Ph[wave];
  u16* PlW = Pl[wave];

  const int sr = tid >> 3;                         // staging row 0..63
  const int sc = ((tid & 7) ^ (sr & 7)) * 8;       // swizzled source k-chunk
  for (int kt = 0; kt < 16; ++kt) {
    __syncthreads();
    {
      const size_t off = (size_t)wave * 1024;      // bytes; +lane*16 by HW
      const size_t kg = ((size_t)b * 1024 + kt * 64 + sr) * 3072 + 1024 + h * 64 + sc;
      gload16(QKh + kg, (char*)Kh + off);
      gload16(QKl + kg, (char*)Kl + off);
      const size_t vg = ((size_t)(b * 16 + h) * 64 + sr) * 1024 + kt * 64 + sc;
      gload16(Vth + vg, (char*)Vh + off);
      gload16(Vtl + vg, (char*)Vl + off);
    }
    __syncthreads();
    float pm[4][4];
    #pragma unroll
    for (int jn = 0; jn < 4; ++jn) {
      floatx4 a = zero;
      #pragma unroll
      for (int kk = 0; kk < 2; ++kk) {
        const int n = jn * 16 + i15;
        const int ch = ((kk * 4 + quad) ^ (n & 7)) * 8;
        const short8 bh = *(const short8*)&Kh[n * 64 + ch];
        const short8 bl = *(const short8*)&Kl[n * 64 + ch];
        a = __builtin_amdgcn_mfma_f32_16x16x32_bf16(qh[kk], bh, a, 0, 0, 0);
        a = __builtin_amdgcn_mfma_f32_16x16x32_bf16(ql[kk], bh, a, 0, 0, 0);
        a = __builtin_amdgcn_mfma_f32_16x16x32_bf16(qh[kk], bl, a, 0, 0, 0);
      }
      #pragma unroll
      for (int r = 0; r < 4; ++r) pm[jn][r] = a[r] * stot[r];
    }
    float alpha[4];
    #pragma unroll
    for (int r = 0; r < 4; ++r) {
      float mx = fmaxf(fmaxf(pm[0][r], pm[1][r]), fmaxf(pm[2][r], pm[3][r]));
      mx = fmaxf(mx, __shfl_xor(mx, 1));
      mx = fmaxf(mx, __shfl_xor(mx, 2));
      mx = fmaxf(mx, __shfl_xor(mx, 4));
      mx = fmaxf(mx, __shfl_xor(mx, 8));
      const float mn = fmaxf(m_r[r], mx);
      alpha[r] = __expf(m_r[r] - mn);
      m_r[r] = mn;
      float rs = 0.f;
      #pragma unroll
      for (int jn = 0; jn < 4; ++jn) { pm[jn][r] = __expf(pm[jn][r] - mn); rs += pm[jn][r]; }
      rs += __shfl_xor(rs, 1);
      rs += __shfl_xor(rs, 2);
      rs += __shfl_xor(rs, 4);
      rs += __shfl_xor(rs, 8);
      l_r[r] = l_r[r] * alpha[r] + rs;
    }
    #pragma unroll
    for (int f = 0; f < 4; ++f)
      #pragma unroll
      for (int r = 0; r < 4; ++r) Of[f][r] *= alpha[r];
    #pragma unroll
    for (int kk = 0; kk < 2; ++kk) {
      #pragma unroll
      for (int jj = 0; jj < 2; ++jj) {
        const int jn = kk * 2 + jj;
        #pragma unroll
        for (int r = 0; r < 4; ++r) {
          const int a = (quad * 4 + r) * 40 + jj * 16 + i15;
          const u16 hh = f2bf(pm[jn][r]);
          PhW[a] = hh;
          PlW[a] = f2bf(pm[jn][r] - bf2f(hh));
        }
      }
      const short8 pah = *(const short8*)&PhW[i15 * 40 + quad * 8];
      const short8 pal = *(const short8*)&PlW[i15 * 40 + quad * 8];
      #pragma unroll
      for (int f = 0; f < 4; ++f) {
        const int d = f * 16 + i15;
        const int ch = ((kk * 4 + quad) ^ (d & 7)) * 8;
        const short8 vbh = *(const short8*)&Vh[d * 64 + ch];
        const short8 vbl = *(const short8*)&Vl[d * 64 + ch];
        Of[f] = __builtin_amdgcn_mfma_f32_16x16x32_bf16(pah, vbh, Of[f], 0, 0, 0);
        Of[f] = __builtin_amdgcn_mfma_f32_16x16x32_bf16(pal, vbh, Of[f], 0, 0, 0);
        Of[f] = __builtin_amdgcn_mfma_f32_16x16x32_bf16(pah, vbl, Of[f], 0, 0, 0);
      }
    }
  }
  float inv[4];
  #pragma unroll
  for (int r = 0; r < 4; ++r) inv[r] = 1.f / l_r[r];
  #pragma unroll
  for (int f = 0; f < 4; ++f)
    #pragma unroll
    for (int r = 0; r < 4; ++r) {
      const size_t row = (size_t)b * 1024 + qt * 128 + wave * 16 + quad * 4 + r;
      const int col = h * 64 + f * 16 + i15;
      const float val = Of[f][r] * inv[r];
      AOf[row * 1024 + col] = val;
      const u16 hh = f2bf(val);
      AOh[row * 1024 + col] = hh;
      AOl[row * 1024 + col] = f2bf(val - bf2f(hh));
    }
}

// ---------------------------------------------------------------------------
// x = LN(a + b) * g + beta -> fp32 + bf16; then wave 0 computes the MoE router
// for this token, replicating the old moe_gate_kernel bit-exactly (same fp32
// values read from LDS, same FMA order, same shuffle reduction tree).
// ---------------------------------------------------------------------------
__global__ __launch_bounds__(256) void ln_add_router_kernel(
    const float* __restrict__ A, const float* __restrict__ Bp,
    const float* __restrict__ g, const float* __restrict__ beta,
    float* __restrict__ outf, u16* __restrict__ outh,
    const float* __restrict__ gw, const float* __restrict__ gb,
    int* __restrict__ e_sel) {
  __shared__ float xrow[DMODEL];
  int t = blockIdx.x, tid = threadIdx.x;
  const float* a = A + (size_t)t * DMODEL;
  const float* b = Bp + (size_t)t * DMODEL;
  float v[4]; float s = 0.f;
  #pragma unroll
  for (int i = 0; i < 4; ++i) { int d = tid + i*256; v[i] = a[d] + b[d]; s += v[i]; }
  s = blockReduceSum256(s);
  float mean = s * (1.f/1024.f);
  float q = 0.f;
  #pragma unroll
  for (int i = 0; i < 4; ++i) { float df = v[i]-mean; q += df*df; }
  q = blockReduceSum256(q);
  float rstd = rsqrtf(q*(1.f/1024.f) + 1e-5f);
  #pragma unroll
  for (int i = 0; i < 4; ++i) {
    int d = tid + i*256;
    float val = (v[i]-mean)*rstd*g[d] + beta[d];
    outf[(size_t)t*DMODEL + d] = val;
    outh[(size_t)t*DMODEL + d] = f2bf(val);
    xrow[d] = val;
  }
  __syncthreads();
  if (tid < 64) {
    float acc[NEXP] = {};
    for (int d = tid; d < DMODEL; d += 64) {
      float xv = xrow[d];
      const float* gr = gw + (size_t)d * NEXP;
      #pragma unroll
      for (int e = 0; e < NEXP; ++e) acc[e] += xv * gr[e];
    }
    #pragma unroll
    for (int e = 0; e < NEXP; ++e) {
      #pragma unroll
      for (int off = 32; off; off >>= 1) acc[e] += __shfl_down(acc[e], off);
    }
    if (tid == 0) {
      float lg[NEXP];
      #pragma unroll
      for (int e = 0; e < NEXP; ++e) lg[e] = acc[e] + gb[e];
      int i1 = 0;
      for (int e = 1; e < NEXP; ++e) if (lg[e] > lg[i1]) i1 = e;
      int i2 = -1;
      for (int e = 0; e < NEXP; ++e) {
        if (e == i1) continue;
        if (i2 < 0 || lg[e] > lg[i2]) i2 = e;
      }
      e_sel[t] = (i1 > i2) ? i1 : i2;
    }
  }
}

// ---------------------------------------------------------------------------
// Final fused kernel: y = (p0+p1 + b2[e])*rs[e] + x ; out = LN(x + y, n2)
// ---------------------------------------------------------------------------
__global__ __launch_bounds__(256) void ln_final_kernel(
    const float* __restrict__ X, const float* __restrict__ P0,
    const float* __restrict__ P1, const float* __restrict__ B2,
    const float* __restrict__ rsv, const int* __restrict__ e_sel,
    const float* __restrict__ g, const float* __restrict__ beta,
    float* __restrict__ out) {
  int t = blockIdx.x, tid = threadIdx.x;
  const int e = e_sel[t];
  const float rse = rsv[e];
  const float* b2e = B2 + (size_t)e * DMODEL;
  const int d0 = tid * 4;
  const size_t base = (size_t)t * DMODEL + d0;
  const float4 xv = *(const float4*)&X[base];
  const float4 p0v = *(const float4*)&P0[base];
  const float4 p1v = *(const float4*)&P1[base];
  const float4 bv = *(const float4*)&b2e[d0];
  float v[4]; float s = 0.f;
  v[0] = 2.f*xv.x + (p0v.x + p1v.x + bv.x) * rse;
  v[1] = 2.f*xv.y + (p0v.y + p1v.y + bv.y) * rse;
  v[2] = 2.f*xv.z + (p0v.z + p1v.z + bv.z) * rse;
  v[3] = 2.f*xv.w + (p0v.w + p1v.w + bv.w) * rse;
  s = v[0] + v[1] + v[2] + v[3];
  s = blockReduceSum256(s);
  float mean = s * (1.f/1024.f);
  float q = 0.f;
  #pragma unroll
  for (int i = 0; i < 4; ++i) { float df = v[i]-mean; q += df*df; }
  q = blockReduceSum256(q);
  float rstd = rsqrtf(q*(1.f/1024.f) + 1e-5f);
  const float4 g4 = *(const float4*)&g[d0];
  const float4 be4 = *(const float4*)&beta[d0];
  float4 o;
  o.x = (v[0]-mean)*rstd*g4.x + be4.x;
  o.y = (v[1]-mean)*rstd*g4.y + be4.y;
  o.z = (v[2]-mean)*rstd*g4.z + be4.z;
  o.w = (v[3]-mean)*rstd*g4.w + be4.w;
  *(float4*)&out[base] = o;
}

__global__ __launch_bounds__(256) void moe_group_kernel(
    const int* __restrict__ e_sel, int* __restrict__ perm,
    int* __restrict__ g_offs, int* __restrict__ g_counts) {
  __shared__ int cnt[NEXP], offs[NEXP], cur[NEXP];
  int tid = threadIdx.x;
  if (tid < NEXP) cnt[tid] = 0;
  __syncthreads();
  for (int t = tid; t < TOK; t += 256) atomicAdd(&cnt[e_sel[t]], 1);
  __syncthreads();
  if (tid == 0) {
    int run = 0;
    for (int e = 0; e < NEXP; ++e) { offs[e] = run; cur[e] = run; run += cnt[e]; }
  }
  __syncthreads();
  if (tid < NEXP) { g_offs[tid] = offs[tid]; g_counts[tid] = cnt[tid]; }
  for (int t = tid; t < TOK; t += 256) {
    int pos = atomicAdd(&cur[e_sel[t]], 1);
    perm[pos] = t;
  }
}

// LN over DFF (per selected expert) + exact-erf GELU, in place on bf16 h.
__global__ __launch_bounds__(256) void moe_ln_gelu_kernel(
    u16* __restrict__ H, const float* __restrict__ ln_g,
    const float* __restrict__ ln_b, const int* __restrict__ e_sel) {
  int t = blockIdx.x, tid = threadIdx.x;
  int e = e_sel[t];
  u16* hp = H + (size_t)t * DFFN;
  float v[16]; float s = 0.f;
  #pragma unroll
  for (int i = 0; i < 4; ++i) {
    const int d = i * 1024 + tid * 4;
    union { uint2 u; u16 q[4]; } hv;
    hv.u = *(const uint2*)&hp[d];
    #pragma unroll
    for (int j = 0; j < 4; ++j) { v[i*4+j] = bf2f(hv.q[j]); s += v[i*4+j]; }
  }
  s = blockReduceSum256(s);
  float mean = s * (1.f/4096.f);
  float q = 0.f;
  #pragma unroll
  for (int i = 0; i < 16; ++i) { float df = v[i]-mean; q += df*df; }
  q = blockReduceSum256(q);
  float rstd = rsqrtf(q*(1.f/4096.f) + 1e-5f);
  const float* gg = ln_g + (size_t)e * DFFN;
  const float* bb = ln_b + (size_t)e * DFFN;
  #pragma unroll
  for (int i = 0; i < 4; ++i) {
    const int d = i * 1024 + tid * 4;
    const float4 g4 = *(const float4*)&gg[d];
    const float4 b4 = *(const float4*)&bb[d];
    const float gf[4] = {g4.x, g4.y, g4.z, g4.w};
    const float bf[4] = {b4.x, b4.y, b4.z, b4.w};
    union { uint2 u; u16 q[4]; } ov;
    #pragma unroll
    for (int j = 0; j < 4; ++j) {
      float xx = (v[i*4+j]-mean)*rstd*gf[j] + bf[j];
      ov.q[j] = f2bf(0.5f * xx * (1.f + erff(xx * 0.7071067811865475f)));
    }
    *(uint2*)&hp[d] = ov.u;
  }
}

// ---------------------------------------------------------------------------
extern "C" void kernel_launch(void* const* d_in, const int* in_sizes, int n_in,
                              void* d_out, int out_size, void* d_ws, size_t ws_size,
                              hipStream_t stream) {
  (void)in_sizes; (void)n_in; (void)out_size; (void)ws_size;
  const float* src    = (const float*)d_in[0];
  const float* qw     = (const float*)d_in[1];
  const float* kw     = (const float*)d_in[2];
  const float* vw     = (const float*)d_in[3];
  const float* ow     = (const float*)d_in[4];
  const float* gate_w = (const float*)d_in[5];
  const float* gate_b = (const float*)d_in[6];
  const float* scale_w= (const float*)d_in[7];
  const float* n1_g   = (const float*)d_in[8];
  const float* n1_b   = (const float*)d_in[9];
  const float* n2_g   = (const float*)d_in[10];
  const float* n2_b   = (const float*)d_in[11];
  const float* mgw    = (const float*)d_in[12];
  const float* mgb    = (const float*)d_in[13];
  const float* w1     = (const float*)d_in[14];
  const float* b1     = (const float*)d_in[15];
  const float* ln_g   = (const float*)d_in[16];
  const float* ln_b   = (const float*)d_in[17];
  const float* w2     = (const float*)d_in[18];
  const float* b2     = (const float*)d_in[19];
  const float* rs     = (const float*)d_in[20];

  char* ws = (char*)d_ws;
  const size_t MB = 1024 * 1024;
  // flat layout (no aliasing; ws >= 512 MB per harness fill)
  u16*   src_hi = (u16*)(ws + 0*MB);    // 4
  u16*   src_lo = (u16*)(ws + 4*MB);    // 4
  u16*   Wt3_hi = (u16*)(ws + 8*MB);    // 6
  u16*   Wt3_lo = (u16*)(ws + 14*MB);   // 6
  u16*   gw_hi  = (u16*)(ws + 20*MB);   // 2
  u16*   gw_lo  = (u16*)(ws + 22*MB);   // 2
  u16*   ow_hi  = (u16*)(ws + 24*MB);   // 2
  u16*   ow_lo  = (u16*)(ws + 26*MB);   // 2
  u16*   W1A    = (u16*)(ws + 28*MB);   // 64
  u16*   W2A    = (u16*)(ws + 92*MB);   // 64
  u16*   qkv_hi = (u16*)(ws + 156*MB);  // 12
  u16*   qkv_lo = (u16*)(ws + 168*MB);  // 12
  u16*   Vt_hi  = (u16*)(ws + 180*MB);  // 4
  u16*   Vt_lo  = (u16*)(ws + 184*MB);  // 4
  float* ao     = (float*)(ws + 188*MB);// 8
  u16*   ao_hi  = (u16*)(ws + 196*MB);  // 4
  u16*   ao_lo  = (u16*)(ws + 200*MB);  // 4
  u16*   gb_hi  = (u16*)(ws + 204*MB);  // 4
  u16*   gb_lo  = (u16*)(ws + 208*MB);  // 4
  float* proj   = (float*)(ws + 212*MB);// 8
  float* x      = (float*)(ws + 220*MB);// 8
  u16*   x_hi   = (u16*)(ws + 228*MB);  // 4
  u16*   h      = (u16*)(ws + 232*MB);  // 16
  float* p0     = (float*)(ws + 248*MB);// 8
  float* p1     = (float*)(ws + 256*MB);// 8
  int*   e_sel  = (int*)(ws + 264*MB);
  int*   perm   = e_sel + TOK;
  int*   offs   = perm + TOK;
  int*   cnts   = offs + NEXP;

  dim3 blk(256);

  // 1. all streaming input transforms (split + QKV/gate/ow convs + w1 conv)
  prep_kernel<<<15360, blk, 0, stream>>>(src, src_hi, src_lo,
      qw, kw, vw, Wt3_hi, Wt3_lo, gate_w, gw_hi, gw_lo, ow, ow_hi, ow_lo,
      w1, W1A);

  // 2. fused QKV GEMM (V written directly transposed)
  gemm_split_kernel<2,64><<<dim3(48,16), blk, 0, stream>>>(src_hi, src_lo,
      Wt3_hi, Wt3_lo, nullptr, nullptr, nullptr, qkv_hi, qkv_lo, Vt_hi, Vt_lo,
      TOK, 3072, DMODEL);

  // 3. flash attention (pure; no hosted conv strips)
  attn_mfma_kernel<<<dim3(8, NHEAD, 2), dim3(512), 0, stream>>>(
      qkv_hi, qkv_lo, Vt_hi, Vt_lo, scale_w, ao, ao_hi, ao_lo);

  // 4. gate GEMM + hosted w2 conversion (K half 0)
  gemm_split_w2_kernel<1><<<512, blk, 0, stream>>>(ao_hi, ao_lo, gw_hi, gw_lo,
      gate_b, ao, nullptr, gb_hi, gb_lo, w2, W2A, 0);

  // 5. ow GEMM + hosted w2 conversion (K half 1)
  gemm_split_w2_kernel<0><<<512, blk, 0, stream>>>(gb_hi, gb_lo, ow_hi, ow_lo,
      nullptr, nullptr, proj, nullptr, nullptr, w2, W2A, 1);

  // 6. x = LN(src + proj) (+bf16) + router (bit-exact replica of moe_gate)
  ln_add_router_kernel<<<TOK, blk, 0, stream>>>(src, proj, n1_g, n1_b, x, x_hi,
      mgw, mgb, e_sel);

  // 7. grouping
  moe_group_kernel<<<1, blk, 0, stream>>>(e_sel, perm, offs, cnts);

  // 8. FFN1, all 8 experts in one launch
  gemm_moe_kernel<0,128><<<dim3(DFFN/128, 16, 8), blk, 0, stream>>>(
      x_hi, W1A, b1, perm, offs, cnts, h, nullptr, nullptr, DFFN, DMODEL);

  // 9. LN+GELU
  moe_ln_gelu_kernel<<<TOK, blk, 0, stream>>>(h, ln_g, ln_b, e_sel);

  // 10. FFN2, all 8 experts x 2-way split-K in one launch
  gemm_moe_kernel<1,64><<<dim3(DMODEL/64, 16, 16), blk, 0, stream>>>(
      h, W2A, nullptr, perm, offs, cnts, nullptr, p0, p1, DMODEL, DFFN);

  // 11. out = LN(x + ((p0+p1+b2[e])*rs[e] + x), n2)
  ln_final_kernel<<<TOK, blk, 0, stream>>>(x, p0, p1, b2, rs, e_sel, n2_g, n2_b,
      (float*)d_out);
}

// Round 6
// 699.393 us; speedup vs baseline: 1.0589x; 1.0199x over previous
//
#include <hip/hip_runtime.h>
#include <math.h>

// Problem constants (fixed by the reference)
#define TOK    2048      // B*S
#define DMODEL 1024
#define NHEAD  16
#define HDIM   64
#define NEXP   8
#define DFFN   4096

typedef unsigned short u16;
typedef __attribute__((ext_vector_type(8))) short short8;   // 8 bf16 (4 VGPRs)
typedef __attribute__((ext_vector_type(4))) float floatx4;  // MFMA C/D

__device__ __forceinline__ float sigmoidf_(float x) { return 1.f / (1.f + __expf(-x)); }

__device__ __forceinline__ u16 f2bf(float f) {               // RNE fp32->bf16
  union { float f; unsigned u; } v; v.f = f;
  unsigned r = v.u + 0x7FFFu + ((v.u >> 16) & 1u);
  return (u16)(r >> 16);
}
__device__ __forceinline__ float bf2f(u16 h) {
  union { unsigned u; float f; } v; v.u = ((unsigned)h) << 16; return v.f;
}

// async global->LDS, 16B per lane; LDS dest = wave-uniform base + lane*16
__device__ __forceinline__ void gload16(const void* g, void* l) {
  __builtin_amdgcn_global_load_lds((const __attribute__((address_space(1))) void*)g,
                                   (__attribute__((address_space(3))) void*)l, 16, 0, 0);
}

// block = 256 threads (4 waves). Broadcast result to all threads.
__device__ __forceinline__ float blockReduceSum256(float val) {
  __shared__ float ws_[4];
  #pragma unroll
  for (int off = 32; off; off >>= 1) val += __shfl_down(val, off);
  int lane = threadIdx.x & 63, w = threadIdx.x >> 6;
  if (lane == 0) ws_[w] = val;
  __syncthreads();
  float r = ws_[0] + ws_[1] + ws_[2] + ws_[3];
  __syncthreads();
  return r;
}

// ---------------------------------------------------------------------------
// Prep mega-kernel (all streaming input transforms, one BW-bound launch):
//  blocks [0,2048):      src fp32 -> (src_hi, src_lo) split
//  blocks [2048,5120):   QKV weight conv+transpose -> Wt3 hi/lo  (32x32 tiles)
//  blocks [5120,7168):   gate_w / ow conv+transpose -> hi/lo     (32x32 tiles)
//  blocks [7168,15360):  w1 conv+transpose -> W1b bf16           (64x64 tiles,
//                        fully coalesced loads/stores, 2-way-free LDS banks)
// ---------------------------------------------------------------------------
__global__ __launch_bounds__(256) void prep_kernel(
    const float* __restrict__ src, u16* __restrict__ Shi, u16* __restrict__ Slo,
    const float* __restrict__ Qw, const float* __restrict__ Kw, const float* __restrict__ Vw,
    u16* __restrict__ W3h, u16* __restrict__ W3l,
    const float* __restrict__ Gw, u16* __restrict__ Gh, u16* __restrict__ Gl,
    const float* __restrict__ Ow, u16* __restrict__ Oh, u16* __restrict__ Ol,
    const float* __restrict__ W1, u16* __restrict__ W1b) {
  const int bid = blockIdx.x, tid = threadIdx.x;
  __shared__ float tile[64][65];
  if (bid < 2048) {                               // ---- split path
    const int i = bid * 256 + tid;
    const float4 v = ((const float4*)src)[i];
    const float f[4] = {v.x, v.y, v.z, v.w};
    union { u16 s[4]; uint2 u; } h, l;
    #pragma unroll
    for (int j = 0; j < 4; ++j) {
      h.s[j] = f2bf(f[j]);
      l.s[j] = f2bf(f[j] - bf2f(h.s[j]));
    }
    ((uint2*)Shi)[i] = h.u;
    ((uint2*)Slo)[i] = l.u;
    return;
  }
  if (bid < 7168) {                               // ---- 32x32 split weight conv
    const float* W; u16 *Whp, *Wlp; int n0, k0;
    if (bid < 5120) {                             // QKV weights
      const int t = bid - 2048;
      const int z = t >> 5;                       // 0..95
      const int zz = z >> 5;                      // 0,1,2
      W = (zz == 0) ? Qw : (zz == 1) ? Kw : Vw;
      Whp = W3h + (size_t)zz * DMODEL * DMODEL;
      Wlp = W3l + (size_t)zz * DMODEL * DMODEL;
      n0 = (t & 31) * 32; k0 = (z & 31) * 32;
    } else {                                      // gate_w / ow
      const int t = bid - 5120;
      const int t2 = t & 1023;
      if (t < 1024) { W = Gw; Whp = Gh; Wlp = Gl; }
      else          { W = Ow; Whp = Oh; Wlp = Ol; }
      n0 = (t2 & 31) * 32; k0 = (t2 >> 5) * 32;
    }
    const int r = tid >> 3, c4 = (tid & 7) * 4;
    const float4 v = *(const float4*)&W[(size_t)(k0 + r) * DMODEL + n0 + c4];
    tile[r][c4+0] = v.x; tile[r][c4+1] = v.y; tile[r][c4+2] = v.z; tile[r][c4+3] = v.w;
    __syncthreads();
    union { u16 s[4]; uint2 u; } h, l;
    #pragma unroll
    for (int j = 0; j < 4; ++j) {
      const float f = tile[c4 + j][r];
      h.s[j] = f2bf(f);
      l.s[j] = f2bf(f - bf2f(h.s[j]));
    }
    *(uint2*)&Whp[(size_t)(n0 + r) * DMODEL + k0 + c4] = h.u;
    *(uint2*)&Wlp[(size_t)(n0 + r) * DMODEL + k0 + c4] = l.u;
    return;
  }
  // ---- w1 conv: 64x64 tile. w1[e][k][n] fp32 -> W1b[e][n][k] bf16.
  // Loads: per instr, 4 rows x 256B contiguous (16 lanes/row).
  // Stores: per instr, 8 output rows x 128B contiguous (8 lanes/row).
  const int bid2 = bid - 7168;                    // 0..8191
  const int e = bid2 >> 10;                       // 1024 blocks/expert
  const int rem = bid2 & 1023;
  const int n0 = (rem & 63) * 64;                 // 64 n-tiles
  const int k0 = (rem >> 6) * 64;                 // 16 k-tiles
  const float* W = W1 + (size_t)e * DMODEL * DFFN;
  u16* O = W1b + (size_t)e * DFFN * DMODEL;
  {
    const int lr = tid >> 4;                      // 0..15
    const int lc = (tid & 15) * 4;                // 0..60
    #pragma unroll
    for (int p = 0; p < 4; ++p) {
      const float4 v = *(const float4*)&W[(size_t)(k0 + p * 16 + lr) * DFFN + n0 + lc];
      tile[p*16 + lr][lc+0] = v.x; tile[p*16 + lr][lc+1] = v.y;
      tile[p*16 + lr][lc+2] = v.z; tile[p*16 + lr][lc+3] = v.w;
    }
  }
  __syncthreads();
  {
    const int kl = (tid & 7) * 8;                 // k chunk within tile
    const int nl = tid >> 3;                      // 0..31
    #pragma unroll
    for (int q = 0; q < 2; ++q) {
      const int n = q * 32 + nl;
      union { u16 s[8]; uint4 u; } o;
      #pragma unroll
      for (int j = 0; j < 8; ++j) o.s[j] = f2bf(tile[kl + j][n]);
      *(uint4*)&O[(size_t)(n0 + n) * DMODEL + k0 + kl] = o.u;
    }
  }
}

// ---------------------------------------------------------------------------
// Split-precision bf16 MFMA GEMM body: C[M,N] = A[M,K] @ W[K,N].
// acc += Ah*Wh + Al*Wh + Ah*Wl  (error ~2^-18, protects MoE routing).
// Tile TM(M) x TN(N), BK=64, 4 waves 2x2 (wave tile TM/2 x TN/2), 16x16x32.
// LDS chunk-swizzle: chunk c of row m holds global k-chunk (c ^ (m&7)).
// EPI 0: Cf = acc. EPI 1: split(sigmoid(acc+bias)*mul). EPI 2: QKV (V transposed).
// Per-element arithmetic identical for any TM/TN (same K order, same MFMA seq).
// ---------------------------------------------------------------------------
template<int EPI, int TM, int TN>
__device__ __forceinline__ void gemm_split_body(
    u16* Ah, u16* Al, u16* Bh, u16* Bl, int bx, int by,
    const u16* __restrict__ Ahi, const u16* __restrict__ Alo,
    const u16* __restrict__ Whi, const u16* __restrict__ Wlo,
    const float* __restrict__ bias, const float* __restrict__ mul,
    float* __restrict__ Cf, u16* __restrict__ Chi, u16* __restrict__ Clo,
    u16* __restrict__ Vth, u16* __restrict__ Vtl,
    int M, int N, int K) {
  constexpr int MI = TM / 32;                    // A m-frags per wave
  constexpr int NF = TN / 32;                    // B n-frags per wave
  const int tid = threadIdx.x;
  const int lane = tid & 63, wave = tid >> 6;
  const int row0 = by * TM, col0 = bx * TN;
  const int wm = (wave & 1) * (TM / 2), wn = (wave >> 1) * (TN / 2);
  const int mr = tid >> 3;                       // staging row 0..31 (+p*32)
  const int ksrc = (tid & 7) ^ ((tid >> 3) & 7); // swizzled source k-chunk
  const floatx4 zero = {0.f, 0.f, 0.f, 0.f};
  floatx4 acc[MI][NF];
  #pragma unroll
  for (int i = 0; i < MI; ++i)
    #pragma unroll
    for (int j = 0; j < NF; ++j) acc[i][j] = zero;

  for (int k0 = 0; k0 < K; k0 += 64) {
    __syncthreads();
    #pragma unroll
    for (int p = 0; p < MI; ++p) {              // A: TM rows
      const size_t ga = (size_t)(row0 + p * 32 + mr) * K + (k0 + ksrc * 8);
      const size_t off = (size_t)(p * 256 + wave * 64) * 16;
      gload16(Ahi + ga, (char*)Ah + off);
      gload16(Alo + ga, (char*)Al + off);
    }
    #pragma unroll
    for (int p = 0; p < NF; ++p) {              // B: TN rows
      const size_t gb = (size_t)(col0 + p * 32 + mr) * K + (k0 + ksrc * 8);
      const size_t off = (size_t)(p * 256 + wave * 64) * 16;
      gload16(Whi + gb, (char*)Bh + off);
      gload16(Wlo + gb, (char*)Bl + off);
    }
    __syncthreads();
    #pragma unroll
    for (int kk = 0; kk < 2; ++kk) {
      short8 ah[MI], al[MI], bh[NF], bl[NF];
      #pragma unroll
      for (int i = 0; i < MI; ++i) {
        const int ml = wm + i * 16 + (lane & 15);
        const int cm = (kk * 4 + (lane >> 4)) ^ (ml & 7);
        ah[i] = *(const short8*)&Ah[ml * 64 + cm * 8];
        al[i] = *(const short8*)&Al[ml * 64 + cm * 8];
      }
      #pragma unroll
      for (int j = 0; j < NF; ++j) {
        const int nl = wn + j * 16 + (lane & 15);
        const int cn = (kk * 4 + (lane >> 4)) ^ (nl & 7);
        bh[j] = *(const short8*)&Bh[nl * 64 + cn * 8];
        bl[j] = *(const short8*)&Bl[nl * 64 + cn * 8];
      }
      #pragma unroll
      for (int i = 0; i < MI; ++i)
        #pragma unroll
        for (int j = 0; j < NF; ++j) {
          acc[i][j] = __builtin_amdgcn_mfma_f32_16x16x32_bf16(ah[i], bh[j], acc[i][j], 0, 0, 0);
          acc[i][j] = __builtin_amdgcn_mfma_f32_16x16x32_bf16(al[i], bh[j], acc[i][j], 0, 0, 0);
          acc[i][j] = __builtin_amdgcn_mfma_f32_16x16x32_bf16(ah[i], bl[j], acc[i][j], 0, 0, 0);
        }
    }
  }
  const int cl = lane & 15, quad = lane >> 4;
  if (EPI == 2 && col0 >= 2048) {
    // V region: transposed store into Vt[bh][d][tok] (hi/lo), 8B packed.
    #pragma unroll
    for (int i = 0; i < MI; ++i)
      #pragma unroll
      for (int j = 0; j < NF; ++j) {
        const int dg = col0 + wn + j * 16 + cl - 2048;
        const int bh_ = dg >> 6, d = dg & 63;
        const int row = row0 + wm + i * 16 + quad * 4;   // +r, 4 consecutive toks
        const int b = row >> 10, t0 = row & 1023;
        union { u16 s[4]; uint2 u; } hh, ll;
        #pragma unroll
        for (int r = 0; r < 4; ++r) {
          const float v = acc[i][j][r];
          hh.s[r] = f2bf(v);
          ll.s[r] = f2bf(v - bf2f(hh.s[r]));
        }
        const size_t base = ((size_t)(b * 16 + bh_) * 64 + d) * 1024 + t0;
        *(uint2*)&Vth[base] = hh.u;
        *(uint2*)&Vtl[base] = ll.u;
      }
    return;
  }
  #pragma unroll
  for (int i = 0; i < MI; ++i)
    #pragma unroll
    for (int j = 0; j < NF; ++j) {
      const int col = col0 + wn + j * 16 + cl;
      #pragma unroll
      for (int r = 0; r < 4; ++r) {
        const int row = row0 + wm + i * 16 + quad * 4 + r;
        const float v = acc[i][j][r];
        if (EPI == 0) {
          Cf[(size_t)row * N + col] = v;
        } else if (EPI == 1) {
          const float s = sigmoidf_(v + bias[col]);
          const float g = s * mul[(size_t)row * N + col];
          const u16 hh = f2bf(g);
          Chi[(size_t)row * N + col] = hh;
          Clo[(size_t)row * N + col] = f2bf(g - bf2f(hh));
        } else {
          const u16 hh = f2bf(v);
          Chi[(size_t)row * N + col] = hh;
          Clo[(size_t)row * N + col] = f2bf(v - bf2f(hh));
        }
      }
    }
}

// Pure GEMM wrapper (QKV path, TM=128).
template<int EPI, int TN>
__global__ __launch_bounds__(256, 3) void gemm_split_kernel(
    const u16* __restrict__ Ahi, const u16* __restrict__ Alo,
    const u16* __restrict__ Whi, const u16* __restrict__ Wlo,
    const float* __restrict__ bias, const float* __restrict__ mul,
    float* __restrict__ Cf, u16* __restrict__ Chi, u16* __restrict__ Clo,
    u16* __restrict__ Vth, u16* __restrict__ Vtl,
    int M, int N, int K) {
  __shared__ u16 Ah[128*64], Al[128*64], Bh[TN*64], Bl[TN*64];
  gemm_split_body<EPI, 128, TN>(Ah, Al, Bh, Bl, blockIdx.x, blockIdx.y,
      Ahi, Alo, Whi, Wlo, bias, mul, Cf, Chi, Clo, Vth, Vtl, M, N, K);
}

// GEMM (2048x1024x1024, TM=64, TN=64) + hosted w2-conversion strips.
// blocks [0,512): gemm (32 M-tiles x 16 N-tiles -> 2 blocks/CU);
// blocks [512,768): w2 conv (khalf selects K range).
// TM=64 gives 512 gemm blocks so CUs hold 2-3 blocks: TLP hides barrier drain
// (round-4 lesson: 256 blocks = 1/CU starved the gemm).
struct GemmShared64 { u16 Ah[64*64]; u16 Al[64*64]; u16 Bh[64*64]; u16 Bl[64*64]; };
template<int EPI>
__global__ __launch_bounds__(256, 4) void gemm_split_w2_kernel(
    const u16* __restrict__ Ahi, const u16* __restrict__ Alo,
    const u16* __restrict__ Whi, const u16* __restrict__ Wlo,
    const float* __restrict__ bias, const float* __restrict__ mul,
    float* __restrict__ Cf, u16* __restrict__ Chi, u16* __restrict__ Clo,
    const float* __restrict__ W2, u16* __restrict__ W2b, int khalf) {
  __shared__ union { GemmShared64 g; float tile[32][33]; } sm;
  const int bid = blockIdx.x;
  if (bid < 512) {
    gemm_split_body<EPI, 64, 64>(sm.g.Ah, sm.g.Al, sm.g.Bh, sm.g.Bl,
        bid & 15, bid >> 4,
        Ahi, Alo, Whi, Wlo, bias, mul, Cf, Chi, Clo, nullptr, nullptr,
        TOK, DMODEL, DMODEL);
    return;
  }
  // w2 conv strip: 32 n-cols x 2048 k rows. w2[e][k][n] fp32 -> [e][n][k] bf16.
  const int t = bid - 512;                // 0..255
  const int e = t >> 5, n0 = (t & 31) * 32;
  const float* W = W2 + (size_t)e * DFFN * DMODEL;
  u16* O = W2b + (size_t)e * DMODEL * DFFN;
  const int r = threadIdx.x >> 3, c4 = (threadIdx.x & 7) * 4;
  for (int kt = 0; kt < 64; ++kt) {
    const int k0 = khalf * 2048 + kt * 32;
    __syncthreads();
    const float4 v = *(const float4*)&W[(size_t)(k0 + r) * DMODEL + n0 + c4];
    sm.tile[r][c4+0] = v.x; sm.tile[r][c4+1] = v.y;
    sm.tile[r][c4+2] = v.z; sm.tile[r][c4+3] = v.w;
    __syncthreads();
    union { u16 s[4]; uint2 u; } h4;
    #pragma unroll
    for (int j = 0; j < 4; ++j) h4.s[j] = f2bf(sm.tile[c4 + j][r]);
    *(uint2*)&O[(size_t)(n0 + r) * DFFN + k0 + c4] = h4.u;
  }
}

// ---------------------------------------------------------------------------
// Grouped MoE GEMM, plain bf16 MFMA. Tile 128(M) x TN(N), 4 waves 2x2.
// EPI 0 (ffn1): z = expert (8); full K. Hout = bf16(acc + bias[e][n]).
// EPI 1 (ffn2): z = e + 8*ks (16): 2-way split-K; P[ks][tok*N+col] = acc fp32.
// ---------------------------------------------------------------------------
template<int EPI, int TN>
__global__ __launch_bounds__(256, TN == 64 ? 4 : 3) void gemm_moe_kernel(
    const u16* __restrict__ A, const u16* __restrict__ Wt,
    const float* __restrict__ bias,
    const int* __restrict__ perm, const int* __restrict__ offs,
    const int* __restrict__ counts,
    u16* __restrict__ Hout, float* __restrict__ P0, float* __restrict__ P1,
    int N, int K) {
  constexpr int NF = TN / 32;
  const int z = blockIdx.z;
  const int e = (EPI == 0) ? z : (z & 7);
  const int ks = (EPI == 0) ? 0 : (z >> 3);
  const int ne = counts[e];
  const int tm = blockIdx.y;
  if (tm * 128 >= ne) return;
  const int kbeg = (EPI == 0) ? 0 : ks * (K >> 1);
  const int kend = (EPI == 0) ? K : kbeg + (K >> 1);
  __shared__ u16 As_[128*64], Bs_[TN*64];
  __shared__ int toks[128];
  const int tid = threadIdx.x;
  if (tid < 128) {
    const int idx = tm * 128 + tid;
    toks[tid] = perm[offs[e] + (idx < ne ? idx : 0)];
  }
  __syncthreads();
  const int lane = tid & 63, wave = tid >> 6;
  const int wm = (wave & 1) * 64, wn = (wave >> 1) * (TN / 2);
  const int mr = tid >> 3;
  const int ksrc = (tid & 7) ^ ((tid >> 3) & 7);
  size_t abase[4];
  #pragma unroll
  for (int p = 0; p < 4; ++p) abase[p] = (size_t)toks[p * 32 + mr] * K;
  const u16* We = Wt + (size_t)e * N * K;
  const int col0 = blockIdx.x * TN;
  const floatx4 zero = {0.f, 0.f, 0.f, 0.f};
  floatx4 acc[4][NF];
  #pragma unroll
  for (int i = 0; i < 4; ++i)
    #pragma unroll
    for (int j = 0; j < NF; ++j) acc[i][j] = zero;

  for (int k0 = kbeg; k0 < kend; k0 += 64) {
    __syncthreads();
    #pragma unroll
    for (int p = 0; p < 4; ++p) {
      const size_t off = (size_t)(p * 256 + wave * 64) * 16;
      gload16(A + abase[p] + (k0 + ksrc * 8), (char*)As_ + off);
    }
    #pragma unroll
    for (int p = 0; p < NF; ++p) {
      const size_t off = (size_t)(p * 256 + wave * 64) * 16;
      gload16(We + (size_t)(col0 + p * 32 + mr) * K + (k0 + ksrc * 8), (char*)Bs_ + off);
    }
    __syncthreads();
    #pragma unroll
    for (int kk = 0; kk < 2; ++kk) {
      short8 a[4], b[NF];
      #pragma unroll
      for (int i = 0; i < 4; ++i) {
        const int ml = wm + i * 16 + (lane & 15);
        const int cm = (kk * 4 + (lane >> 4)) ^ (ml & 7);
        a[i] = *(const short8*)&As_[ml * 64 + cm * 8];
      }
      #pragma unroll
      for (int j = 0; j < NF; ++j) {
        const int nl = wn + j * 16 + (lane & 15);
        const int cn = (kk * 4 + (lane >> 4)) ^ (nl & 7);
        b[j] = *(const short8*)&Bs_[nl * 64 + cn * 8];
      }
      #pragma unroll
      for (int i = 0; i < 4; ++i)
        #pragma unroll
        for (int j = 0; j < NF; ++j)
          acc[i][j] = __builtin_amdgcn_mfma_f32_16x16x32_bf16(a[i], b[j], acc[i][j], 0, 0, 0);
    }
  }
  const int cl = lane & 15, quad = lane >> 4;
  float* Pp = (EPI == 1) ? (ks ? P1 : P0) : nullptr;
  #pragma unroll
  for (int i = 0; i < 4; ++i)
    #pragma unroll
    for (int j = 0; j < NF; ++j) {
      const int col = col0 + wn + j * 16 + cl;
      #pragma unroll
      for (int r = 0; r < 4; ++r) {
        const int rl = wm + i * 16 + quad * 4 + r;
        if (tm * 128 + rl < ne) {
          const int tok = toks[rl];
          if (EPI == 0)
            Hout[(size_t)tok * N + col] = f2bf(acc[i][j][r] + bias[(size_t)e * N + col]);
          else
            Pp[(size_t)tok * N + col] = acc[i][j][r];
        }
      }
    }
}

// ---------------------------------------------------------------------------
// MFMA flash attention, split-bf16 (error ~1e-5: protects router decisions).
// grid = (S/128, H, B), block = 512 (8 waves; wave w owns q-rows w*16..w*16+15).
// PURE kernel — no hosted conv strips (round-3 lesson).
// ---------------------------------------------------------------------------
__global__ __launch_bounds__(512, 2) void attn_mfma_kernel(
    const u16* __restrict__ QKh, const u16* __restrict__ QKl,
    const u16* __restrict__ Vth, const u16* __restrict__ Vtl,
    const float* __restrict__ scale_w,
    float* __restrict__ AOf, u16* __restrict__ AOh, u16* __restrict__ AOl) {
  const int qt = blockIdx.x, h = blockIdx.y, b = blockIdx.z;
  __shared__ u16 Kh[64*64], Kl[64*64], Vh[64*64], Vl[64*64];   // 32 KB
  __shared__ u16 Ph[8][16*40], Pl[8][16*40];                   // 20 KB
  const int tid = threadIdx.x, lane = tid & 63, wave = tid >> 6;
  const int i15 = lane & 15, quad = lane >> 4;
  const floatx4 zero = {0.f, 0.f, 0.f, 0.f};

  short8 qh[2], ql[2];
  const size_t qrow = ((size_t)b * 1024 + qt * 128 + wave * 16 + i15) * 3072 + h * 64;
  #pragma unroll
  for (int kk = 0; kk < 2; ++kk) {
    qh[kk] = *(const short8*)&QKh[qrow + kk * 32 + quad * 8];
    ql[kk] = *(const short8*)&QKl[qrow + kk * 32 + quad * 8];
  }
  float dot = 0.f;
  #pragma unroll
  for (int kk = 0; kk < 2; ++kk)
    #pragma unroll
    for (int j = 0; j < 8; ++j) {
      const float sw = scale_w[h * 64 + kk * 32 + quad * 8 + j];
      dot += (bf2f((u16)qh[kk][j]) + bf2f((u16)ql[kk][j])) * sw;
    }
  dot += __shfl_xor(dot, 16);
  dot += __shfl_xor(dot, 32);
  const float g = 2.f * sigmoidf_(dot) * 0.125f;
  float stot[4];
  #pragma unroll
  for (int r = 0; r < 4; ++r) stot[r] = __shfl(g, (lane >> 4) * 4 + r);

  float m_r[4], l_r[4];
  floatx4 Of[4];
  #pragma unroll
  for (int r = 0; r < 4; ++r) { m_r[r] = -1e30f; l_r[r] = 0.f; }
  #pragma unroll
  for (int f = 0; f < 4; ++f) Of[f] = zero;
  u16* PhW = Ph[wave];
  u16* PlW = Pl[wave];

  const int sr = tid >> 3;                         // staging row 0..63
  const int sc = ((tid & 7) ^ (sr & 7)) * 8;       // swizzled source k-chunk
  for (int kt = 0; kt < 16; ++kt) {
    __syncthreads();
    {
      const size_t off = (size_t)wave * 1024;      // bytes; +lane*16 by HW
      const size_t kg = ((size_t)b * 1024 + kt * 64 + sr) * 3072 + 1024 + h * 64 + sc;
      gload16(QKh + kg, (char*)Kh + off);
      gload16(QKl + kg, (char*)Kl + off);
      const size_t vg = ((size_t)(b * 16 + h) * 64 + sr) * 1024 + kt * 64 + sc;
      gload16(Vth + vg, (char*)Vh + off);
      gload16(Vtl + vg, (char*)Vl + off);
    }
    __syncthreads();
    float pm[4][4];
    #pragma unroll
    for (int jn = 0; jn < 4; ++jn) {
      floatx4 a = zero;
      #pragma unroll
      for (int kk = 0; kk < 2; ++kk) {
        const int n = jn * 16 + i15;
        const int ch = ((kk * 4 + quad) ^ (n & 7)) * 8;
        const short8 bh = *(const short8*)&Kh[n * 64 + ch];
        const short8 bl = *(const short8*)&Kl[n * 64 + ch];
        a = __builtin_amdgcn_mfma_f32_16x16x32_bf16(qh[kk], bh, a, 0, 0, 0);
        a = __builtin_amdgcn_mfma_f32_16x16x32_bf16(ql[kk], bh, a, 0, 0, 0);
        a = __builtin_amdgcn_mfma_f32_16x16x32_bf16(qh[kk], bl, a, 0, 0, 0);
      }
      #pragma unroll
      for (int r = 0; r < 4; ++r) pm[jn][r] = a[r] * stot[r];
    }
    float alpha[4];
    #pragma unroll
    for (int r = 0; r < 4; ++r) {
      float mx = fmaxf(fmaxf(pm[0][r], pm[1][r]), fmaxf(pm[2][r], pm[3][r]));
      mx = fmaxf(mx, __shfl_xor(mx, 1));
      mx = fmaxf(mx, __shfl_xor(mx, 2));
      mx = fmaxf(mx, __shfl_xor(mx, 4));
      mx = fmaxf(mx, __shfl_xor(mx, 8));
      const float mn = fmaxf(m_r[r], mx);
      alpha[r] = __expf(m_r[r] - mn);
      m_r[r] = mn;
      float rs = 0.f;
      #pragma unroll
      for (int jn = 0; jn < 4; ++jn) { pm[jn][r] = __expf(pm[jn][r] - mn); rs += pm[jn][r]; }
      rs += __shfl_xor(rs, 1);
      rs += __shfl_xor(rs, 2);
      rs += __shfl_xor(rs, 4);
      rs += __shfl_xor(rs, 8);
      l_r[r] = l_r[r] * alpha[r] + rs;
    }
    #pragma unroll
    for (int f = 0; f < 4; ++f)
      #pragma unroll
      for (int r = 0; r < 4; ++r) Of[f][r] *= alpha[r];
    #pragma unroll
    for (int kk = 0; kk < 2; ++kk) {
      #pragma unroll
      for (int jj = 0; jj < 2; ++jj) {
        const int jn = kk * 2 + jj;
        #pragma unroll
        for (int r = 0; r < 4; ++r) {
          const int a = (quad * 4 + r) * 40 + jj * 16 + i15;
          const u16 hh = f2bf(pm[jn][r]);
          PhW[a] = hh;
          PlW[a] = f2bf(pm[jn][r] - bf2f(hh));
        }
      }
      const short8 pah = *(const short8*)&PhW[i15 * 40 + quad * 8];
      const short8 pal = *(const short8*)&PlW[i15 * 40 + quad * 8];
      #pragma unroll
      for (int f = 0; f < 4; ++f) {
        const int d = f * 16 + i15;
        const int ch = ((kk * 4 + quad) ^ (d & 7)) * 8;
        const short8 vbh = *(const short8*)&Vh[d * 64 + ch];
        const short8 vbl = *(const short8*)&Vl[d * 64 + ch];
        Of[f] = __builtin_amdgcn_mfma_f32_16x16x32_bf16(pah, vbh, Of[f], 0, 0, 0);
        Of[f] = __builtin_amdgcn_mfma_f32_16x16x32_bf16(pal, vbh, Of[f], 0, 0, 0);
        Of[f] = __builtin_amdgcn_mfma_f32_16x16x32_bf16(pah, vbl, Of[f], 0, 0, 0);
      }
    }
  }
  float inv[4];
  #pragma unroll
  for (int r = 0; r < 4; ++r) inv[r] = 1.f / l_r[r];
  #pragma unroll
  for (int f = 0; f < 4; ++f)
    #pragma unroll
    for (int r = 0; r < 4; ++r) {
      const size_t row = (size_t)b * 1024 + qt * 128 + wave * 16 + quad * 4 + r;
      const int col = h * 64 + f * 16 + i15;
      const float val = Of[f][r] * inv[r];
      AOf[row * 1024 + col] = val;
      const u16 hh = f2bf(val);
      AOh[row * 1024 + col] = hh;
      AOl[row * 1024 + col] = f2bf(val - bf2f(hh));
    }
}

// ---------------------------------------------------------------------------
// x = LN(a + b) * g + beta -> fp32 + bf16; then wave 0 computes the MoE router
// for this token, replicating the old moe_gate_kernel bit-exactly.
// ---------------------------------------------------------------------------
__global__ __launch_bounds__(256) void ln_add_router_kernel(
    const float* __restrict__ A, const float* __restrict__ Bp,
    const float* __restrict__ g, const float* __restrict__ beta,
    float* __restrict__ outf, u16* __restrict__ outh,
    const float* __restrict__ gw, const float* __restrict__ gb,
    int* __restrict__ e_sel) {
  __shared__ float xrow[DMODEL];
  int t = blockIdx.x, tid = threadIdx.x;
  const float* a = A + (size_t)t * DMODEL;
  const float* b = Bp + (size_t)t * DMODEL;
  float v[4]; float s = 0.f;
  #pragma unroll
  for (int i = 0; i < 4; ++i) { int d = tid + i*256; v[i] = a[d] + b[d]; s += v[i]; }
  s = blockReduceSum256(s);
  float mean = s * (1.f/1024.f);
  float q = 0.f;
  #pragma unroll
  for (int i = 0; i < 4; ++i) { float df = v[i]-mean; q += df*df; }
  q = blockReduceSum256(q);
  float rstd = rsqrtf(q*(1.f/1024.f) + 1e-5f);
  #pragma unroll
  for (int i = 0; i < 4; ++i) {
    int d = tid + i*256;
    float val = (v[i]-mean)*rstd*g[d] + beta[d];
    outf[(size_t)t*DMODEL + d] = val;
    outh[(size_t)t*DMODEL + d] = f2bf(val);
    xrow[d] = val;
  }
  __syncthreads();
  if (tid < 64) {
    float acc[NEXP] = {};
    for (int d = tid; d < DMODEL; d += 64) {
      float xv = xrow[d];
      const float* gr = gw + (size_t)d * NEXP;
      #pragma unroll
      for (int e = 0; e < NEXP; ++e) acc[e] += xv * gr[e];
    }
    #pragma unroll
    for (int e = 0; e < NEXP; ++e) {
      #pragma unroll
      for (int off = 32; off; off >>= 1) acc[e] += __shfl_down(acc[e], off);
    }
    if (tid == 0) {
      float lg[NEXP];
      #pragma unroll
      for (int e = 0; e < NEXP; ++e) lg[e] = acc[e] + gb[e];
      int i1 = 0;
      for (int e = 1; e < NEXP; ++e) if (lg[e] > lg[i1]) i1 = e;
      int i2 = -1;
      for (int e = 0; e < NEXP; ++e) {
        if (e == i1) continue;
        if (i2 < 0 || lg[e] > lg[i2]) i2 = e;
      }
      e_sel[t] = (i1 > i2) ? i1 : i2;
    }
  }
}

// ---------------------------------------------------------------------------
// Final fused kernel: y = (p0+p1 + b2[e])*rs[e] + x ; out = LN(x + y, n2)
// ---------------------------------------------------------------------------
__global__ __launch_bounds__(256) void ln_final_kernel(
    const float* __restrict__ X, const float* __restrict__ P0,
    const float* __restrict__ P1, const float* __restrict__ B2,
    const float* __restrict__ rsv, const int* __restrict__ e_sel,
    const float* __restrict__ g, const float* __restrict__ beta,
    float* __restrict__ out) {
  int t = blockIdx.x, tid = threadIdx.x;
  const int e = e_sel[t];
  const float rse = rsv[e];
  const float* b2e = B2 + (size_t)e * DMODEL;
  const int d0 = tid * 4;
  const size_t base = (size_t)t * DMODEL + d0;
  const float4 xv = *(const float4*)&X[base];
  const float4 p0v = *(const float4*)&P0[base];
  const float4 p1v = *(const float4*)&P1[base];
  const float4 bv = *(const float4*)&b2e[d0];
  float v[4]; float s = 0.f;
  v[0] = 2.f*xv.x + (p0v.x + p1v.x + bv.x) * rse;
  v[1] = 2.f*xv.y + (p0v.y + p1v.y + bv.y) * rse;
  v[2] = 2.f*xv.z + (p0v.z + p1v.z + bv.z) * rse;
  v[3] = 2.f*xv.w + (p0v.w + p1v.w + bv.w) * rse;
  s = v[0] + v[1] + v[2] + v[3];
  s = blockReduceSum256(s);
  float mean = s * (1.f/1024.f);
  float q = 0.f;
  #pragma unroll
  for (int i = 0; i < 4; ++i) { float df = v[i]-mean; q += df*df; }
  q = blockReduceSum256(q);
  float rstd = rsqrtf(q*(1.f/1024.f) + 1e-5f);
  const float4 g4 = *(const float4*)&g[d0];
  const float4 be4 = *(const float4*)&beta[d0];
  float4 o;
  o.x = (v[0]-mean)*rstd*g4.x + be4.x;
  o.y = (v[1]-mean)*rstd*g4.y + be4.y;
  o.z = (v[2]-mean)*rstd*g4.z + be4.z;
  o.w = (v[3]-mean)*rstd*g4.w + be4.w;
  *(float4*)&out[base] = o;
}

__global__ __launch_bounds__(256) void moe_group_kernel(
    const int* __restrict__ e_sel, int* __restrict__ perm,
    int* __restrict__ g_offs, int* __restrict__ g_counts) {
  __shared__ int cnt[NEXP], offs[NEXP], cur[NEXP];
  int tid = threadIdx.x;
  if (tid < NEXP) cnt[tid] = 0;
  __syncthreads();
  for (int t = tid; t < TOK; t += 256) atomicAdd(&cnt[e_sel[t]], 1);
  __syncthreads();
  if (tid == 0) {
    int run = 0;
    for (int e = 0; e < NEXP; ++e) { offs[e] = run; cur[e] = run; run += cnt[e]; }
  }
  __syncthreads();
  if (tid < NEXP) { g_offs[tid] = offs[tid]; g_counts[tid] = cnt[tid]; }
  for (int t = tid; t < TOK; t += 256) {
    int pos = atomicAdd(&cur[e_sel[t]], 1);
    perm[pos] = t;
  }
}

// LN over DFF (per selected expert) + exact-erf GELU, in place on bf16 h.
__global__ __launch_bounds__(256) void moe_ln_gelu_kernel(
    u16* __restrict__ H, const float* __restrict__ ln_g,
    const float* __restrict__ ln_b, const int* __restrict__ e_sel) {
  int t = blockIdx.x, tid = threadIdx.x;
  int e = e_sel[t];
  u16* hp = H + (size_t)t * DFFN;
  float v[16]; float s = 0.f;
  #pragma unroll
  for (int i = 0; i < 4; ++i) {
    const int d = i * 1024 + tid * 4;
    union { uint2 u; u16 q[4]; } hv;
    hv.u = *(const uint2*)&hp[d];
    #pragma unroll
    for (int j = 0; j < 4; ++j) { v[i*4+j] = bf2f(hv.q[j]); s += v[i*4+j]; }
  }
  s = blockReduceSum256(s);
  float mean = s * (1.f/4096.f);
  float q = 0.f;
  #pragma unroll
  for (int i = 0; i < 16; ++i) { float df = v[i]-mean; q += df*df; }
  q = blockReduceSum256(q);
  float rstd = rsqrtf(q*(1.f/4096.f) + 1e-5f);
  const float* gg = ln_g + (size_t)e * DFFN;
  const float* bb = ln_b + (size_t)e * DFFN;
  #pragma unroll
  for (int i = 0; i < 4; ++i) {
    const int d = i * 1024 + tid * 4;
    const float4 g4 = *(const float4*)&gg[d];
    const float4 b4 = *(const float4*)&bb[d];
    const float gf[4] = {g4.x, g4.y, g4.z, g4.w};
    const float bf[4] = {b4.x, b4.y, b4.z, b4.w};
    union { uint2 u; u16 q[4]; } ov;
    #pragma unroll
    for (int j = 0; j < 4; ++j) {
      float xx = (v[i*4+j]-mean)*rstd*gf[j] + bf[j];
      ov.q[j] = f2bf(0.5f * xx * (1.f + erff(xx * 0.7071067811865475f)));
    }
    *(uint2*)&hp[d] = ov.u;
  }
}

// ---------------------------------------------------------------------------
extern "C" void kernel_launch(void* const* d_in, const int* in_sizes, int n_in,
                              void* d_out, int out_size, void* d_ws, size_t ws_size,
                              hipStream_t stream) {
  (void)in_sizes; (void)n_in; (void)out_size; (void)ws_size;
  const float* src    = (const float*)d_in[0];
  const float* qw     = (const float*)d_in[1];
  const float* kw     = (const float*)d_in[2];
  const float* vw     = (const float*)d_in[3];
  const float* ow     = (const float*)d_in[4];
  const float* gate_w = (const float*)d_in[5];
  const float* gate_b = (const float*)d_in[6];
  const float* scale_w= (const float*)d_in[7];
  const float* n1_g   = (const float*)d_in[8];
  const float* n1_b   = (const float*)d_in[9];
  const float* n2_g   = (const float*)d_in[10];
  const float* n2_b   = (const float*)d_in[11];
  const float* mgw    = (const float*)d_in[12];
  const float* mgb    = (const float*)d_in[13];
  const float* w1     = (const float*)d_in[14];
  const float* b1     = (const float*)d_in[15];
  const float* ln_g   = (const float*)d_in[16];
  const float* ln_b   = (const float*)d_in[17];
  const float* w2     = (const float*)d_in[18];
  const float* b2     = (const float*)d_in[19];
  const float* rs     = (const float*)d_in[20];

  char* ws = (char*)d_ws;
  const size_t MB = 1024 * 1024;
  // flat layout (no aliasing; ws >= 512 MB per harness fill)
  u16*   src_hi = (u16*)(ws + 0*MB);    // 4
  u16*   src_lo = (u16*)(ws + 4*MB);    // 4
  u16*   Wt3_hi = (u16*)(ws + 8*MB);    // 6
  u16*   Wt3_lo = (u16*)(ws + 14*MB);   // 6
  u16*   gw_hi  = (u16*)(ws + 20*MB);   // 2
  u16*   gw_lo  = (u16*)(ws + 22*MB);   // 2
  u16*   ow_hi  = (u16*)(ws + 24*MB);   // 2
  u16*   ow_lo  = (u16*)(ws + 26*MB);   // 2
  u16*   W1A    = (u16*)(ws + 28*MB);   // 64
  u16*   W2A    = (u16*)(ws + 92*MB);   // 64
  u16*   qkv_hi = (u16*)(ws + 156*MB);  // 12
  u16*   qkv_lo = (u16*)(ws + 168*MB);  // 12
  u16*   Vt_hi  = (u16*)(ws + 180*MB);  // 4
  u16*   Vt_lo  = (u16*)(ws + 184*MB);  // 4
  float* ao     = (float*)(ws + 188*MB);// 8
  u16*   ao_hi  = (u16*)(ws + 196*MB);  // 4
  u16*   ao_lo  = (u16*)(ws + 200*MB);  // 4
  u16*   gb_hi  = (u16*)(ws + 204*MB);  // 4
  u16*   gb_lo  = (u16*)(ws + 208*MB);  // 4
  float* proj   = (float*)(ws + 212*MB);// 8
  float* x      = (float*)(ws + 220*MB);// 8
  u16*   x_hi   = (u16*)(ws + 228*MB);  // 4
  u16*   h      = (u16*)(ws + 232*MB);  // 16
  float* p0     = (float*)(ws + 248*MB);// 8
  float* p1     = (float*)(ws + 256*MB);// 8
  int*   e_sel  = (int*)(ws + 264*MB);
  int*   perm   = e_sel + TOK;
  int*   offs   = perm + TOK;
  int*   cnts   = offs + NEXP;

  dim3 blk(256);

  // 1. all streaming input transforms (split + QKV/gate/ow convs + w1 conv)
  prep_kernel<<<15360, blk, 0, stream>>>(src, src_hi, src_lo,
      qw, kw, vw, Wt3_hi, Wt3_lo, gate_w, gw_hi, gw_lo, ow, ow_hi, ow_lo,
      w1, W1A);

  // 2. fused QKV GEMM (V written directly transposed)
  gemm_split_kernel<2,64><<<dim3(48,16), blk, 0, stream>>>(src_hi, src_lo,
      Wt3_hi, Wt3_lo, nullptr, nullptr, nullptr, qkv_hi, qkv_lo, Vt_hi, Vt_lo,
      TOK, 3072, DMODEL);

  // 3. flash attention (pure; no hosted conv strips)
  attn_mfma_kernel<<<dim3(8, NHEAD, 2), dim3(512), 0, stream>>>(
      qkv_hi, qkv_lo, Vt_hi, Vt_lo, scale_w, ao, ao_hi, ao_lo);

  // 4. gate GEMM (TM=64, 512 blocks) + hosted w2 conversion (K half 0)
  gemm_split_w2_kernel<1><<<768, blk, 0, stream>>>(ao_hi, ao_lo, gw_hi, gw_lo,
      gate_b, ao, nullptr, gb_hi, gb_lo, w2, W2A, 0);

  // 5. ow GEMM (TM=64) + hosted w2 conversion (K half 1)
  gemm_split_w2_kernel<0><<<768, blk, 0, stream>>>(gb_hi, gb_lo, ow_hi, ow_lo,
      nullptr, nullptr, proj, nullptr, nullptr, w2, W2A, 1);

  // 6. x = LN(src + proj) (+bf16) + router (bit-exact replica of moe_gate)
  ln_add_router_kernel<<<TOK, blk, 0, stream>>>(src, proj, n1_g, n1_b, x, x_hi,
      mgw, mgb, e_sel);

  // 7. grouping
  moe_group_kernel<<<1, blk, 0, stream>>>(e_sel, perm, offs, cnts);

  // 8. FFN1, all 8 experts in one launch
  gemm_moe_kernel<0,128><<<dim3(DFFN/128, 16, 8), blk, 0, stream>>>(
      x_hi, W1A, b1, perm, offs, cnts, h, nullptr, nullptr, DFFN, DMODEL);

  // 9. LN+GELU
  moe_ln_gelu_kernel<<<TOK, blk, 0, stream>>>(h, ln_g, ln_b, e_sel);

  // 10. FFN2, all 8 experts x 2-way split-K in one launch
  gemm_moe_kernel<1,64><<<dim3(DMODEL/64, 16, 16), blk, 0, stream>>>(
      h, W2A, nullptr, perm, offs, cnts, nullptr, p0, p1, DMODEL, DFFN);

  // 11. out = LN(x + ((p0+p1+b2[e])*rs[e] + x), n2)
  ln_final_kernel<<<TOK, blk, 0, stream>>>(x, p0, p1, b2, rs, e_sel, n2_g, n2_b,
      (float*)d_out);
}